// Round 2
// baseline (1243.029 us; speedup 1.0000x reference)
//
#include <hip/hip_runtime.h>
#include <hip/hip_bf16.h>
#include <math.h>

#define B_  2
#define L_  1024
#define D_  1024
#define H_  16
#define DH_ 64
#define M_  (B_*L_)   // 2048

#define KSCALE (0.02f/32.0f)   // /sqrt(D) * 0.02

// ---------------- fused projection GEMM (fp32) ----------------
// C0 = x@Wq + bq ; C1 = x@Wk1 + bk1 ; C2 = sigmoid((x@Wk2 + bk2) * KSCALE)
__global__ __launch_bounds__(256) void proj_gemm(
    const float* __restrict__ A,
    const float* __restrict__ W0, const float* __restrict__ b0,
    const float* __restrict__ W1, const float* __restrict__ b1,
    const float* __restrict__ W2, const float* __restrict__ b2,
    float* __restrict__ C0, float* __restrict__ C1o, float* __restrict__ C2o)
{
  const int BM=64, BN=64, BK=16;
  __shared__ float As[BK][BM+4];
  __shared__ float Bs0[BK][BN+4];
  __shared__ float Bs1[BK][BN+4];
  __shared__ float Bs2[BK][BN+4];
  int tid = threadIdx.x;
  int tx = tid & 15, ty = tid >> 4;
  int rowBase = blockIdx.x * BM;
  int colBase = blockIdx.y * BN;
  float acc0[4][4]={}, acc1[4][4]={}, acc2[4][4]={};
  for (int k0 = 0; k0 < D_; k0 += BK) {
    #pragma unroll
    for (int j = 0; j < 4; ++j) {
      int idx = tid + j*256;
      int r = idx >> 4, kk = idx & 15;
      As[kk][r] = A[(size_t)(rowBase + r)*D_ + k0 + kk];
    }
    #pragma unroll
    for (int j = 0; j < 4; ++j) {
      int idx = tid + j*256;
      int kk = idx >> 6, c = idx & 63;
      Bs0[kk][c] = W0[(size_t)(k0+kk)*D_ + colBase + c];
      Bs1[kk][c] = W1[(size_t)(k0+kk)*D_ + colBase + c];
      Bs2[kk][c] = W2[(size_t)(k0+kk)*D_ + colBase + c];
    }
    __syncthreads();
    #pragma unroll
    for (int kk = 0; kk < BK; ++kk) {
      float a[4], bv0[4], bv1[4], bv2[4];
      #pragma unroll
      for (int i=0;i<4;i++) a[i]  = As[kk][ty*4+i];
      #pragma unroll
      for (int j=0;j<4;j++) { bv0[j]=Bs0[kk][tx*4+j]; bv1[j]=Bs1[kk][tx*4+j]; bv2[j]=Bs2[kk][tx*4+j]; }
      #pragma unroll
      for (int i=0;i<4;i++)
        #pragma unroll
        for(int j=0;j<4;j++){
          acc0[i][j] += a[i]*bv0[j];
          acc1[i][j] += a[i]*bv1[j];
          acc2[i][j] += a[i]*bv2[j];
        }
    }
    __syncthreads();
  }
  #pragma unroll
  for (int i=0;i<4;i++){
    int r = rowBase + ty*4 + i;
    #pragma unroll
    for (int j=0;j<4;j++){
      int c = colBase + tx*4 + j;
      C0[(size_t)r*D_+c]  = acc0[i][j] + b0[c];
      C1o[(size_t)r*D_+c] = acc1[i][j] + b1[c];
      float t = (acc2[i][j] + b2[c]) * KSCALE;
      C2o[(size_t)r*D_+c] = 1.0f/(1.0f + expf(-t));
    }
  }
}

// ---------------- final GEMM (fp32) ----------------
__global__ __launch_bounds__(256) void out_gemm(
    const float* __restrict__ A, const float* __restrict__ W,
    const float* __restrict__ bias, float* __restrict__ C)
{
  const int BM=64, BN=64, BK=16;
  __shared__ float As[BK][BM+4];
  __shared__ float Bs[BK][BN+4];
  int tid = threadIdx.x;
  int tx = tid & 15, ty = tid >> 4;
  int rowBase = blockIdx.x * BM;
  int colBase = blockIdx.y * BN;
  float acc[4][4]={};
  for (int k0 = 0; k0 < D_; k0 += BK) {
    #pragma unroll
    for (int j = 0; j < 4; ++j) {
      int idx = tid + j*256;
      int r = idx >> 4, kk = idx & 15;
      As[kk][r] = A[(size_t)(rowBase + r)*D_ + k0 + kk];
    }
    #pragma unroll
    for (int j = 0; j < 4; ++j) {
      int idx = tid + j*256;
      int kk = idx >> 6, c = idx & 63;
      Bs[kk][c] = W[(size_t)(k0+kk)*D_ + colBase + c];
    }
    __syncthreads();
    #pragma unroll
    for (int kk = 0; kk < BK; ++kk) {
      float a[4], bv[4];
      #pragma unroll
      for (int i=0;i<4;i++) a[i] = As[kk][ty*4+i];
      #pragma unroll
      for (int j=0;j<4;j++) bv[j]= Bs[kk][tx*4+j];
      #pragma unroll
      for (int i=0;i<4;i++)
        #pragma unroll
        for(int j=0;j<4;j++) acc[i][j] += a[i]*bv[j];
    }
    __syncthreads();
  }
  #pragma unroll
  for (int i=0;i<4;i++){
    int r = rowBase + ty*4 + i;
    #pragma unroll
    for (int j=0;j<4;j++){
      int c = colBase + tx*4 + j;
      C[(size_t)r*D_+c] = acc[i][j] + bias[c];
    }
  }
}

// ---------------- per-(b,l,h) scalar gates ----------------
// GL = log(max(sigmoid(x_head . Wg + bg), 1e-6)) ; RR = silu(K_head . Ws + bs)
__global__ __launch_bounds__(256) void scalars_kernel(
  const float* __restrict__ X, const float* __restrict__ K,
  const float* __restrict__ Wg, const float* __restrict__ bg,
  const float* __restrict__ Ws, const float* __restrict__ bs,
  float* __restrict__ GL, float* __restrict__ RR)
{
  int item = blockIdx.x * 4 + (threadIdx.x >> 6);   // [0, M_*H_)
  int ln = threadIdx.x & 63;
  int row = item >> 4;    // b*L + l
  int h = item & 15;
  float xv = X[(size_t)row*D_ + h*64 + ln];
  float kv = K[(size_t)row*D_ + h*64 + ln];
  float gdot = xv * Wg[ln];
  float rdot = kv * Ws[ln];
  #pragma unroll
  for (int off = 32; off; off >>= 1) {
    gdot += __shfl_xor(gdot, off);
    rdot += __shfl_xor(rdot, off);
  }
  if (ln == 0) {
    float glogit = gdot + bg[0];
    float sg = 1.f/(1.f+expf(-glogit));
    sg = fmaxf(sg, 1e-6f);
    GL[item] = logf(sg);
    float rlogit = rdot + bs[0];
    RR[item] = rlogit / (1.f + expf(-rlogit));  // silu
  }
}

// ---------------- serial scan: one block per (b,h) ----------------
__global__ __launch_bounds__(256) void scan_kernel(
  const float* __restrict__ Q, const float* __restrict__ K,
  const float* __restrict__ X, const float* __restrict__ K2,
  const float* __restrict__ GL, const float* __restrict__ RR,
  float* __restrict__ O)
{
  int bh = blockIdx.x; int b = bh >> 4; int h = bh & 15;
  int tid = threadIdx.x;
  int w = tid >> 6, ln = tid & 63;
  __shared__ float q_s[64], k_s[64], v_s[64], k2_s[64], q2_s[64];
  __shared__ float part1[4][64], part2[4][64];
  float S[16], T[16];
  #pragma unroll
  for (int i=0;i<16;i++){S[i]=0.f;T[i]=0.f;}
  float log_cum = 0.f;
  float o1_prev = 0.f;
  const float* qp  = Q  + (size_t)(b*L_)*D_ + h*64;
  const float* kp  = K  + (size_t)(b*L_)*D_ + h*64;
  const float* xp  = X  + (size_t)(b*L_)*D_ + h*64;
  const float* k2p = K2 + (size_t)(b*L_)*D_ + h*64;
  const float* glp = GL + (size_t)(b*L_)*H_ + h;
  const float* rp  = RR + (size_t)(b*L_)*H_ + h;
  float* op = O + (size_t)(b*L_)*D_ + h*64;

  for (int l = 0; l < L_; ++l) {
    float gl = glp[(size_t)l*H_];
    float rv = rp[(size_t)l*H_];
    if (w==0)      q_s[ln] = qp[(size_t)l*D_ + ln];
    else if (w==1) k_s[ln] = kp[(size_t)l*D_ + ln];
    else if (w==2) v_s[ln] = xp[(size_t)l*D_ + ln];
    else { if (l>0) k2_s[ln] = k2p[(size_t)(l-1)*D_ + ln]; }
    __syncthreads();

    // AR branch
    log_cum += gl;
    float lc = fminf(fmaxf(log_cum, -30.f), 30.f);
    float Gc = expf(lc) + 1e-6f;
    float coef = rv / Gc;
    float vln = v_s[ln];
    float t = coef * vln;
    float p1 = 0.f;
    #pragma unroll
    for (int i=0;i<16;i++){
      S[i] += k_s[w*16+i] * t;
      p1   += q_s[w*16+i] * S[i];
    }
    part1[w][ln] = p1;

    // MA branch (uses previous row's k2/q2 and previous O1)
    float p2 = 0.f;
    if (l > 0) {
      float E = vln - o1_prev;
      #pragma unroll
      for (int i=0;i<16;i++){
        T[i] += k2_s[w*16+i] * E;
        p2   += q2_s[w*16+i] * T[i];
      }
    }
    part2[w][ln] = p2;
    __syncthreads();

    float o1 = (part1[0][ln]+part1[1][ln]+part1[2][ln]+part1[3][ln]) * Gc;
    float o2 =  part2[0][ln]+part2[1][ln]+part2[2][ln]+part2[3][ln];
    o1_prev = o1;
    if (w==0) op[(size_t)l*D_ + ln] = o1 + o2;
    else if (w==1) {
      float qv = q_s[ln];
      // q2 = -leaky_relu(-q/8, 0.02) = (q>=0 ? 0.02q : q)/8
      q2_s[ln] = (qv >= 0.f ? 0.02f*qv : qv) * 0.125f;
    }
    __syncthreads();
  }
}

extern "C" void kernel_launch(void* const* d_in, const int* in_sizes, int n_in,
                              void* d_out, int out_size, void* d_ws, size_t ws_size,
                              hipStream_t stream) {
  const float* x  = (const float*)d_in[0];
  const float* Wq = (const float*)d_in[1];
  const float* bq = (const float*)d_in[2];
  const float* Wk1= (const float*)d_in[3];
  const float* bk1= (const float*)d_in[4];
  const float* Wk2= (const float*)d_in[5];
  const float* bk2= (const float*)d_in[6];
  const float* Wg = (const float*)d_in[7];
  const float* bg = (const float*)d_in[8];
  const float* Ws = (const float*)d_in[9];
  const float* bs = (const float*)d_in[10];
  const float* Wp = (const float*)d_in[11];
  const float* bp = (const float*)d_in[12];
  float* out = (float*)d_out;

  float* ws = (float*)d_ws;
  size_t MD = (size_t)M_*D_;
  float* Qb  = ws;
  float* Kb  = Qb  + MD;
  float* K2b = Kb  + MD;
  float* Ob  = K2b + MD;
  float* GLb = Ob  + MD;
  float* RRb = GLb + (size_t)M_*H_;

  dim3 g1(M_/64, D_/64);
  proj_gemm<<<g1, 256, 0, stream>>>(x, Wq,bq, Wk1,bk1, Wk2,bk2, Qb, Kb, K2b);
  scalars_kernel<<<(M_*H_)/4, 256, 0, stream>>>(x, Kb, Wg, bg, Ws, bs, GLb, RRb);
  scan_kernel<<<B_*H_, 256, 0, stream>>>(Qb, Kb, x, K2b, GLb, RRb, Ob);
  out_gemm<<<g1, 256, 0, stream>>>(Ob, Wp, bp, out);
}

// Round 3
// 477.799 us; speedup vs baseline: 2.6016x; 2.6016x over previous
//
#include <hip/hip_runtime.h>
#include <hip/hip_bf16.h>
#include <math.h>

#define B_  2
#define L_  1024
#define D_  1024
#define H_  16
#define DH_ 64
#define M_  (B_*L_)   // 2048
#define CHUNK 64
#define NCH (L_/CHUNK)   // 16

#define KSCALE (0.02f/32.0f)   // /sqrt(D) * 0.02

// ---------------- fused projection GEMM (fp32) ----------------
__global__ __launch_bounds__(256) void proj_gemm(
    const float* __restrict__ A,
    const float* __restrict__ W0, const float* __restrict__ b0,
    const float* __restrict__ W1, const float* __restrict__ b1,
    const float* __restrict__ W2, const float* __restrict__ b2,
    float* __restrict__ C0, float* __restrict__ C1o, float* __restrict__ C2o)
{
  const int BM=64, BN=64, BK=16;
  __shared__ float As[BK][BM+4];
  __shared__ float Bs0[BK][BN+4];
  __shared__ float Bs1[BK][BN+4];
  __shared__ float Bs2[BK][BN+4];
  int tid = threadIdx.x;
  int tx = tid & 15, ty = tid >> 4;
  int rowBase = blockIdx.x * BM;
  int colBase = blockIdx.y * BN;
  float acc0[4][4]={}, acc1[4][4]={}, acc2[4][4]={};
  for (int k0 = 0; k0 < D_; k0 += BK) {
    #pragma unroll
    for (int j = 0; j < 4; ++j) {
      int idx = tid + j*256;
      int r = idx >> 4, kk = idx & 15;
      As[kk][r] = A[(size_t)(rowBase + r)*D_ + k0 + kk];
    }
    #pragma unroll
    for (int j = 0; j < 4; ++j) {
      int idx = tid + j*256;
      int kk = idx >> 6, c = idx & 63;
      Bs0[kk][c] = W0[(size_t)(k0+kk)*D_ + colBase + c];
      Bs1[kk][c] = W1[(size_t)(k0+kk)*D_ + colBase + c];
      Bs2[kk][c] = W2[(size_t)(k0+kk)*D_ + colBase + c];
    }
    __syncthreads();
    #pragma unroll
    for (int kk = 0; kk < BK; ++kk) {
      float a[4], bv0[4], bv1[4], bv2[4];
      #pragma unroll
      for (int i=0;i<4;i++) a[i]  = As[kk][ty*4+i];
      #pragma unroll
      for (int j=0;j<4;j++) { bv0[j]=Bs0[kk][tx*4+j]; bv1[j]=Bs1[kk][tx*4+j]; bv2[j]=Bs2[kk][tx*4+j]; }
      #pragma unroll
      for (int i=0;i<4;i++)
        #pragma unroll
        for(int j=0;j<4;j++){
          acc0[i][j] += a[i]*bv0[j];
          acc1[i][j] += a[i]*bv1[j];
          acc2[i][j] += a[i]*bv2[j];
        }
    }
    __syncthreads();
  }
  #pragma unroll
  for (int i=0;i<4;i++){
    int r = rowBase + ty*4 + i;
    #pragma unroll
    for (int j=0;j<4;j++){
      int c = colBase + tx*4 + j;
      C0[(size_t)r*D_+c]  = acc0[i][j] + b0[c];
      C1o[(size_t)r*D_+c] = acc1[i][j] + b1[c];
      float t = (acc2[i][j] + b2[c]) * KSCALE;
      C2o[(size_t)r*D_+c] = 1.0f/(1.0f + expf(-t));
    }
  }
}

// ---------------- final GEMM (fp32) ----------------
__global__ __launch_bounds__(256) void out_gemm(
    const float* __restrict__ A, const float* __restrict__ W,
    const float* __restrict__ bias, float* __restrict__ C)
{
  const int BM=64, BN=64, BK=16;
  __shared__ float As[BK][BM+4];
  __shared__ float Bs[BK][BN+4];
  int tid = threadIdx.x;
  int tx = tid & 15, ty = tid >> 4;
  int rowBase = blockIdx.x * BM;
  int colBase = blockIdx.y * BN;
  float acc[4][4]={};
  for (int k0 = 0; k0 < D_; k0 += BK) {
    #pragma unroll
    for (int j = 0; j < 4; ++j) {
      int idx = tid + j*256;
      int r = idx >> 4, kk = idx & 15;
      As[kk][r] = A[(size_t)(rowBase + r)*D_ + k0 + kk];
    }
    #pragma unroll
    for (int j = 0; j < 4; ++j) {
      int idx = tid + j*256;
      int kk = idx >> 6, c = idx & 63;
      Bs[kk][c] = W[(size_t)(k0+kk)*D_ + colBase + c];
    }
    __syncthreads();
    #pragma unroll
    for (int kk = 0; kk < BK; ++kk) {
      float a[4], bv[4];
      #pragma unroll
      for (int i=0;i<4;i++) a[i] = As[kk][ty*4+i];
      #pragma unroll
      for (int j=0;j<4;j++) bv[j]= Bs[kk][tx*4+j];
      #pragma unroll
      for (int i=0;i<4;i++)
        #pragma unroll
        for(int j=0;j<4;j++) acc[i][j] += a[i]*bv[j];
    }
    __syncthreads();
  }
  #pragma unroll
  for (int i=0;i<4;i++){
    int r = rowBase + ty*4 + i;
    #pragma unroll
    for (int j=0;j<4;j++){
      int c = colBase + tx*4 + j;
      C[(size_t)r*D_+c] = acc[i][j] + bias[c];
    }
  }
}

// ---------------- per-(b,l,h) scalar gates ----------------
__global__ __launch_bounds__(256) void scalars_kernel(
  const float* __restrict__ X, const float* __restrict__ K,
  const float* __restrict__ Wg, const float* __restrict__ bg,
  const float* __restrict__ Ws, const float* __restrict__ bs,
  float* __restrict__ GL, float* __restrict__ RR)
{
  int item = blockIdx.x * 4 + (threadIdx.x >> 6);   // [0, M_*H_)
  int ln = threadIdx.x & 63;
  int row = item >> 4;    // b*L + l
  int h = item & 15;
  float xv = X[(size_t)row*D_ + h*64 + ln];
  float kv = K[(size_t)row*D_ + h*64 + ln];
  float gdot = xv * Wg[ln];
  float rdot = kv * Ws[ln];
  #pragma unroll
  for (int off = 32; off; off >>= 1) {
    gdot += __shfl_xor(gdot, off);
    rdot += __shfl_xor(rdot, off);
  }
  if (ln == 0) {
    float glogit = gdot + bg[0];
    float sg = 1.f/(1.f+expf(-glogit));
    sg = fmaxf(sg, 1e-6f);
    GL[item] = logf(sg);
    float rlogit = rdot + bs[0];
    RR[item] = rlogit / (1.f + expf(-rlogit));  // silu
  }
}

// ---------------- gate prefix scan: Gc and coef per (bh, l) ----------------
// one wave per (b,h); inclusive 64-wide shfl scan, 16 iterations
__global__ __launch_bounds__(256) void gl_scan(
  const float* __restrict__ GL, const float* __restrict__ RR,
  float* __restrict__ GC, float* __restrict__ CF)
{
  int bh = blockIdx.x * 4 + (threadIdx.x >> 6);
  int b = bh >> 4, h = bh & 15;
  int ln = threadIdx.x & 63;
  float carry = 0.f;
  for (int it = 0; it < 16; ++it) {
    int l = it*64 + ln;
    float x = GL[((size_t)(b*L_ + l))*H_ + h];
    #pragma unroll
    for (int off = 1; off < 64; off <<= 1) {
      float t = __shfl_up(x, off);
      if (ln >= off) x += t;
    }
    float tot = __shfl(x, 63);
    float cum = carry + x;
    carry += tot;
    float lc = fminf(fmaxf(cum, -30.f), 30.f);
    float gc = expf(lc) + 1e-6f;
    GC[(size_t)bh*L_ + l] = gc;
    CF[(size_t)bh*L_ + l] = RR[((size_t)(b*L_ + l))*H_ + h] / gc;
  }
}

// ---------------- chunk outer-product sums ----------------
// CS[bh][c][d][e] = sum_{j in chunk} cf_j * Kk[j][d] * Vv[j][e]   (cf=1 if CF null)
__global__ __launch_bounds__(256) void chunk_sum(
  const float* __restrict__ Kk, const float* __restrict__ Vv,
  const float* __restrict__ CF, float* __restrict__ CS)
{
  int bh = blockIdx.x, c = blockIdx.y;
  int b = bh >> 4, h = bh & 15;
  __shared__ float k_s[64][65];
  __shared__ float v_s[64][65];
  __shared__ float cf_s[64];
  int tid = threadIdx.x;
  int row0 = b*L_ + c*CHUNK;
  const float* kp = Kk + (size_t)row0*D_ + h*64;
  const float* vp = Vv + (size_t)row0*D_ + h*64;
  #pragma unroll
  for (int t = 0; t < 16; ++t) {
    int idx = tid + t*256;
    int j = idx >> 6, d = idx & 63;
    k_s[j][d] = kp[(size_t)j*D_ + d];
    v_s[j][d] = vp[(size_t)j*D_ + d];
  }
  if (CF && tid < 64) cf_s[tid] = CF[(size_t)bh*L_ + c*CHUNK + tid];
  __syncthreads();
  int w = tid >> 6, ln = tid & 63;
  float S[16] = {};
  for (int j = 0; j < 64; ++j) {
    float cv = v_s[j][ln];
    if (CF) cv *= cf_s[j];
    #pragma unroll
    for (int i = 0; i < 16; ++i) S[i] += k_s[j][w*16+i] * cv;
  }
  float* out = CS + ((size_t)bh*NCH + c)*4096;
  #pragma unroll
  for (int i = 0; i < 16; ++i) out[(w*16+i)*64 + ln] = S[i];
}

// ---------------- exclusive prefix over chunk states (in place) ----------------
__global__ __launch_bounds__(256) void scan_chunks(float* __restrict__ CS)
{
  int bh = blockIdx.x;
  float run[16] = {};
  float* base = CS + (size_t)bh*NCH*4096;
  for (int c = 0; c < NCH; ++c) {
    float* p = base + c*4096;
    #pragma unroll
    for (int k = 0; k < 16; ++k) {
      int e = k*256 + threadIdx.x;
      float cur = p[e];
      p[e] = run[k];
      run[k] += cur;
    }
  }
}

// ---------------- AR O1 per chunk: O1 = Gc*(Q@Sc + causal(Q@K^T * cf)@V) ----------------
__global__ __launch_bounds__(256) void ar_o1(
  const float* __restrict__ Q, const float* __restrict__ Kk,
  const float* __restrict__ Vv, const float* __restrict__ CF,
  const float* __restrict__ GC, const float* __restrict__ CS,
  float* __restrict__ O1)
{
  int bh = blockIdx.x, c = blockIdx.y;
  int b = bh >> 4, h = bh & 15;
  __shared__ float q_s[64][65];
  __shared__ float k_s[64][65];   // reused to hold P after stage 1
  __shared__ float v_s[64][65];
  __shared__ float sc_s[64][65];
  __shared__ float cf_s[64], gc_s[64];
  int tid = threadIdx.x;
  int row0 = b*L_ + c*CHUNK;
  const float* qp = Q  + (size_t)row0*D_ + h*64;
  const float* kp = Kk + (size_t)row0*D_ + h*64;
  const float* vp = Vv + (size_t)row0*D_ + h*64;
  const float* scp = CS + ((size_t)bh*NCH + c)*4096;
  #pragma unroll
  for (int t = 0; t < 16; ++t) {
    int idx = tid + t*256;
    int j = idx >> 6, d = idx & 63;
    q_s[j][d]  = qp[(size_t)j*D_ + d];
    k_s[j][d]  = kp[(size_t)j*D_ + d];
    v_s[j][d]  = vp[(size_t)j*D_ + d];
    sc_s[j][d] = scp[idx];
  }
  if (tid < 64) {
    cf_s[tid] = CF[(size_t)bh*L_ + c*CHUNK + tid];
    gc_s[tid] = GC[(size_t)bh*L_ + c*CHUNK + tid];
  }
  __syncthreads();
  int w = tid >> 6, ln = tid & 63;
  // stage 1: P[l][j] = (q_l . k_j) * cf_j, causal (j<=l)
  float p[16];
  #pragma unroll
  for (int i = 0; i < 16; ++i) {
    int l = w*16 + i;
    float acc = 0.f;
    #pragma unroll 8
    for (int d = 0; d < 64; ++d) acc += q_s[l][d] * k_s[ln][d];
    p[i] = (ln <= l) ? acc * cf_s[ln] : 0.f;
  }
  __syncthreads();
  #pragma unroll
  for (int i = 0; i < 16; ++i) k_s[w*16+i][ln] = p[i];
  __syncthreads();
  // stage 2: O1[l][e] = gc_l * (sum_d q[l][d]*Sc[d][e] + sum_j P[l][j]*v[j][e])
  #pragma unroll
  for (int i = 0; i < 16; ++i) {
    int l = w*16 + i;
    float acc = 0.f;
    #pragma unroll 8
    for (int d = 0; d < 64; ++d) acc += q_s[l][d] * sc_s[d][ln];
    #pragma unroll 8
    for (int j = 0; j < 64; ++j) acc += k_s[l][j] * v_s[j][ln];
    O1[(size_t)(row0 + l)*D_ + h*64 + ln] = gc_s[l] * acc;
  }
}

// ---------------- E = x[t+1] - O1[t], zero at t = L-1 ----------------
__global__ __launch_bounds__(256) void e_kernel(
  const float* __restrict__ X, const float* __restrict__ O1, float* __restrict__ E)
{
  int r = blockIdx.x;
  int t = r & (L_-1);
  float4* eo = (float4*)(E + (size_t)r*D_);
  int c4 = threadIdx.x;
  if (t == L_-1) {
    eo[c4] = make_float4(0.f,0.f,0.f,0.f);
  } else {
    const float4* xn = (const float4*)(X  + (size_t)(r+1)*D_);
    const float4* o1 = (const float4*)(O1 + (size_t)r*D_);
    float4 a = xn[c4], b = o1[c4];
    eo[c4] = make_float4(a.x-b.x, a.y-b.y, a.z-b.z, a.w-b.w);
  }
}

// ---------------- MA O2 per chunk, added in place: O1[t+1] += q2_t @ (Tc + causal) ----------------
__global__ __launch_bounds__(256) void ma_o2(
  const float* __restrict__ Q, const float* __restrict__ K2,
  const float* __restrict__ E, const float* __restrict__ CS,
  float* __restrict__ O1)
{
  int bh = blockIdx.x, c = blockIdx.y;
  int b = bh >> 4, h = bh & 15;
  __shared__ float q_s[64][65];   // q2
  __shared__ float k_s[64][65];   // k2, reused for P
  __shared__ float v_s[64][65];   // E
  __shared__ float sc_s[64][65];  // T carry
  int tid = threadIdx.x;
  int row0 = b*L_ + c*CHUNK;
  const float* qp = Q  + (size_t)row0*D_ + h*64;
  const float* kp = K2 + (size_t)row0*D_ + h*64;
  const float* vp = E  + (size_t)row0*D_ + h*64;
  const float* scp = CS + ((size_t)bh*NCH + c)*4096;
  #pragma unroll
  for (int t = 0; t < 16; ++t) {
    int idx = tid + t*256;
    int j = idx >> 6, d = idx & 63;
    float qv = qp[(size_t)j*D_ + d];
    q_s[j][d]  = (qv > 0.f ? 0.02f*qv : qv) * 0.125f;   // ma_q_activation
    k_s[j][d]  = kp[(size_t)j*D_ + d];
    v_s[j][d]  = vp[(size_t)j*D_ + d];
    sc_s[j][d] = scp[idx];
  }
  __syncthreads();
  int w = tid >> 6, ln = tid & 63;
  float p[16];
  #pragma unroll
  for (int i = 0; i < 16; ++i) {
    int l = w*16 + i;
    float acc = 0.f;
    #pragma unroll 8
    for (int d = 0; d < 64; ++d) acc += q_s[l][d] * k_s[ln][d];
    p[i] = (ln <= l) ? acc : 0.f;
  }
  __syncthreads();
  #pragma unroll
  for (int i = 0; i < 16; ++i) k_s[w*16+i][ln] = p[i];
  __syncthreads();
  #pragma unroll
  for (int i = 0; i < 16; ++i) {
    int l = w*16 + i;
    if (c*CHUNK + l < L_-1) {   // valid series positions t = 0..L-2
      float acc = 0.f;
      #pragma unroll 8
      for (int d = 0; d < 64; ++d) acc += q_s[l][d] * sc_s[d][ln];
      #pragma unroll 8
      for (int j = 0; j < 64; ++j) acc += k_s[l][j] * v_s[j][ln];
      O1[(size_t)(row0 + l + 1)*D_ + h*64 + ln] += acc;
    }
  }
}

extern "C" void kernel_launch(void* const* d_in, const int* in_sizes, int n_in,
                              void* d_out, int out_size, void* d_ws, size_t ws_size,
                              hipStream_t stream) {
  const float* x  = (const float*)d_in[0];
  const float* Wq = (const float*)d_in[1];
  const float* bq = (const float*)d_in[2];
  const float* Wk1= (const float*)d_in[3];
  const float* bk1= (const float*)d_in[4];
  const float* Wk2= (const float*)d_in[5];
  const float* bk2= (const float*)d_in[6];
  const float* Wg = (const float*)d_in[7];
  const float* bg = (const float*)d_in[8];
  const float* Ws = (const float*)d_in[9];
  const float* bs = (const float*)d_in[10];
  const float* Wp = (const float*)d_in[11];
  const float* bp = (const float*)d_in[12];
  float* out = (float*)d_out;

  float* ws = (float*)d_ws;
  size_t MD = (size_t)M_*D_;
  float* Qb  = ws;                 // Q projection
  float* Kb  = Qb  + MD;           // K1 projection
  float* K2b = Kb  + MD;           // sigmoid(K2 projection)
  float* O1b = K2b + MD;           // O1, then O1+O2 in place
  float* Eb  = O1b + MD;           // MA residuals
  float* CSb = Eb  + MD;           // chunk states: 32*16*4096
  float* GLb = CSb + (size_t)32*NCH*4096;
  float* RRb = GLb + (size_t)M_*H_;
  float* GCb = RRb + (size_t)M_*H_;
  float* CFb = GCb + (size_t)32*L_;

  dim3 g1(M_/64, D_/64);
  dim3 gc(32, NCH);
  proj_gemm<<<g1, 256, 0, stream>>>(x, Wq,bq, Wk1,bk1, Wk2,bk2, Qb, Kb, K2b);
  scalars_kernel<<<(M_*H_)/4, 256, 0, stream>>>(x, Kb, Wg, bg, Ws, bs, GLb, RRb);
  gl_scan<<<8, 256, 0, stream>>>(GLb, RRb, GCb, CFb);
  // AR branch
  chunk_sum<<<gc, 256, 0, stream>>>(Kb, x, CFb, CSb);
  scan_chunks<<<32, 256, 0, stream>>>(CSb);
  ar_o1<<<gc, 256, 0, stream>>>(Qb, Kb, x, CFb, GCb, CSb, O1b);
  // MA branch
  e_kernel<<<M_, 256, 0, stream>>>(x, O1b, Eb);
  chunk_sum<<<gc, 256, 0, stream>>>(K2b, Eb, nullptr, CSb);
  scan_chunks<<<32, 256, 0, stream>>>(CSb);
  ma_o2<<<gc, 256, 0, stream>>>(Qb, K2b, Eb, CSb, O1b);
  // output projection
  out_gemm<<<g1, 256, 0, stream>>>(O1b, Wp, bp, out);
}

// Round 4
// 296.448 us; speedup vs baseline: 4.1931x; 1.6117x over previous
//
#include <hip/hip_runtime.h>
#include <hip/hip_bf16.h>
#include <math.h>

#define B_  2
#define L_  1024
#define D_  1024
#define H_  16
#define DH_ 64
#define M_  (B_*L_)   // 2048
#define CHUNK 64
#define NCH (L_/CHUNK)   // 16

#define KSCALE (0.02f/32.0f)   // /sqrt(D) * 0.02

using bf16x8 = __attribute__((ext_vector_type(8))) short;
using f32x4  = __attribute__((ext_vector_type(4))) float;

__device__ __forceinline__ unsigned short bf16r(float f){
  union{float f; unsigned int u;} x; x.f = f;
  unsigned int r = x.u + 0x7FFF + ((x.u>>16)&1);
  return (unsigned short)(r>>16);
}

// ---------------- fp32 -> bf16 (row-major, same layout) ----------------
__global__ __launch_bounds__(256) void f32_to_bf16(
  const float* __restrict__ src, unsigned short* __restrict__ dst, int n4)
{
  int i = blockIdx.x*256 + threadIdx.x;
  int stride = gridDim.x*256;
  for (; i < n4; i += stride){
    float4 v = ((const float4*)src)[i];
    ushort4 o;
    o.x = bf16r(v.x); o.y = bf16r(v.y); o.z = bf16r(v.z); o.w = bf16r(v.w);
    ((ushort4*)dst)[i] = o;
  }
}

// ---------------- W fp32 [K][N] -> Wt bf16 [N][K] (4 matrices) ----------------
__global__ __launch_bounds__(256) void convert_wt(
  const float* __restrict__ W0, const float* __restrict__ W1,
  const float* __restrict__ W2, const float* __restrict__ W3,
  unsigned short* __restrict__ T0, unsigned short* __restrict__ T1,
  unsigned short* __restrict__ T2, unsigned short* __restrict__ T3)
{
  int which = blockIdx.z;
  const float* W = which==0?W0: which==1?W1: which==2?W2: W3;
  unsigned short* T = which==0?T0: which==1?T1: which==2?T2: T3;
  __shared__ float tile[64][65];
  int kBase = blockIdx.x*64, nBase = blockIdx.y*64;
  #pragma unroll
  for (int i=0;i<16;i++){
    int idx = threadIdx.x + i*256;
    int r = idx>>6, c = idx&63;
    tile[r][c] = W[(size_t)(kBase+r)*D_ + nBase+c];
  }
  __syncthreads();
  #pragma unroll
  for (int i=0;i<16;i++){
    int idx = threadIdx.x + i*256;
    int n = idx>>6, k = idx&63;
    T[(size_t)(nBase+n)*D_ + kBase+k] = bf16r(tile[k][n]);
  }
}

// ---------------- bf16 MFMA GEMM core: C = A[M][1024] @ Wt[N][1024]^T ----------------
// tile 128(M) x 64(N), BK=32, 256 threads (4 waves), swizzled LDS (slot^((row>>1)&3))
__device__ __forceinline__ void gemm_core(
    const unsigned short* __restrict__ A, const unsigned short* __restrict__ Bt,
    const float* __restrict__ bias, float* __restrict__ C, int epi,
    int rowBase, int colBase)
{
  __shared__ __align__(16) unsigned short As[128*32];
  __shared__ __align__(16) unsigned short Bs[64*32];
  int tid = threadIdx.x, w = tid>>6, l = tid&63;
  int lr = l&15, g4 = l>>4;
  f32x4 acc[2][4];
  #pragma unroll
  for (int mi=0;mi<2;mi++)
    #pragma unroll
    for (int ni=0;ni<4;ni++)
      acc[mi][ni] = (f32x4){0.f,0.f,0.f,0.f};

  for (int k0 = 0; k0 < D_; k0 += 32) {
    #pragma unroll
    for (int i=0;i<2;i++){
      int F = (w*2+i)*64 + l;
      int r = F>>2, c16 = F&3;
      int sc = c16 ^ ((r>>1)&3);
      const unsigned short* g = A + (size_t)(rowBase+r)*D_ + k0 + sc*8;
      __builtin_amdgcn_global_load_lds(
        (const __attribute__((address_space(1))) void*)g,
        (__attribute__((address_space(3))) void*)(As + (size_t)(w*2+i)*512), 16, 0, 0);
    }
    {
      int F = w*64 + l;
      int r = F>>2, c16 = F&3;
      int sc = c16 ^ ((r>>1)&3);
      const unsigned short* g = Bt + (size_t)(colBase+r)*D_ + k0 + sc*8;
      __builtin_amdgcn_global_load_lds(
        (const __attribute__((address_space(1))) void*)g,
        (__attribute__((address_space(3))) void*)(Bs + (size_t)w*512), 16, 0, 0);
    }
    __syncthreads();
    bf16x8 af[2], bfr[4];
    #pragma unroll
    for (int mi=0;mi<2;mi++){
      int row = w*32 + mi*16 + lr;
      af[mi] = *(const bf16x8*)(As + row*32 + ((g4 ^ ((row>>1)&3))*8));
    }
    #pragma unroll
    for (int ni=0;ni<4;ni++){
      int n = ni*16 + lr;
      bfr[ni] = *(const bf16x8*)(Bs + n*32 + ((g4 ^ ((n>>1)&3))*8));
    }
    #pragma unroll
    for (int mi=0;mi<2;mi++)
      #pragma unroll
      for (int ni=0;ni<4;ni++)
        acc[mi][ni] = __builtin_amdgcn_mfma_f32_16x16x32_bf16(af[mi], bfr[ni], acc[mi][ni], 0,0,0);
    __syncthreads();
  }

  #pragma unroll
  for (int mi=0;mi<2;mi++){
    #pragma unroll
    for (int ni=0;ni<4;ni++){
      int col = colBase + ni*16 + lr;
      float bv = bias[col];
      #pragma unroll
      for (int r=0;r<4;r++){
        int row = rowBase + w*32 + mi*16 + g4*4 + r;
        float v = acc[mi][ni][r] + bv;
        if (epi) v = 1.f/(1.f + expf(-v*KSCALE));
        C[(size_t)row*D_ + col] = v;
      }
    }
  }
}

// 3 projections in one launch (z selects weight/output; z==2 applies sigmoid epi)
__global__ __launch_bounds__(256) void gemm3(
  const unsigned short* __restrict__ A,
  const unsigned short* __restrict__ T0, const unsigned short* __restrict__ T1,
  const unsigned short* __restrict__ T2,
  const float* __restrict__ b0, const float* __restrict__ b1, const float* __restrict__ b2,
  float* __restrict__ C0, float* __restrict__ C1, float* __restrict__ C2)
{
  int z = blockIdx.z;
  const unsigned short* Bt = z==0?T0: z==1?T1: T2;
  const float* bias = z==0?b0: z==1?b1: b2;
  float* C = z==0?C0: z==1?C1: C2;
  gemm_core(A, Bt, bias, C, z==2 ? 1 : 0, blockIdx.x*128, blockIdx.y*64);
}

__global__ __launch_bounds__(256) void gemm1(
  const unsigned short* __restrict__ A, const unsigned short* __restrict__ Bt,
  const float* __restrict__ bias, float* __restrict__ C)
{
  gemm_core(A, Bt, bias, C, 0, blockIdx.x*128, blockIdx.y*64);
}

// ---------------- per-(b,l,h) scalar gates ----------------
__global__ __launch_bounds__(256) void scalars_kernel(
  const float* __restrict__ X, const float* __restrict__ K,
  const float* __restrict__ Wg, const float* __restrict__ bg,
  const float* __restrict__ Ws, const float* __restrict__ bs,
  float* __restrict__ GL, float* __restrict__ RR)
{
  int item = blockIdx.x * 4 + (threadIdx.x >> 6);   // [0, M_*H_)
  int ln = threadIdx.x & 63;
  int row = item >> 4;    // b*L + l
  int h = item & 15;
  float xv = X[(size_t)row*D_ + h*64 + ln];
  float kv = K[(size_t)row*D_ + h*64 + ln];
  float gdot = xv * Wg[ln];
  float rdot = kv * Ws[ln];
  #pragma unroll
  for (int off = 32; off; off >>= 1) {
    gdot += __shfl_xor(gdot, off);
    rdot += __shfl_xor(rdot, off);
  }
  if (ln == 0) {
    float glogit = gdot + bg[0];
    float sg = 1.f/(1.f+expf(-glogit));
    sg = fmaxf(sg, 1e-6f);
    GL[item] = logf(sg);
    float rlogit = rdot + bs[0];
    RR[item] = rlogit / (1.f + expf(-rlogit));  // silu
  }
}

// ---------------- gate prefix scan ----------------
__global__ __launch_bounds__(256) void gl_scan(
  const float* __restrict__ GL, const float* __restrict__ RR,
  float* __restrict__ GC, float* __restrict__ CF)
{
  int bh = blockIdx.x * 4 + (threadIdx.x >> 6);
  int b = bh >> 4, h = bh & 15;
  int ln = threadIdx.x & 63;
  float carry = 0.f;
  for (int it = 0; it < 16; ++it) {
    int l = it*64 + ln;
    float x = GL[((size_t)(b*L_ + l))*H_ + h];
    #pragma unroll
    for (int off = 1; off < 64; off <<= 1) {
      float t = __shfl_up(x, off);
      if (ln >= off) x += t;
    }
    float tot = __shfl(x, 63);
    float cum = carry + x;
    carry += tot;
    float lc = fminf(fmaxf(cum, -30.f), 30.f);
    float gc = expf(lc) + 1e-6f;
    GC[(size_t)bh*L_ + l] = gc;
    CF[(size_t)bh*L_ + l] = RR[((size_t)(b*L_ + l))*H_ + h] / gc;
  }
}

// ---------------- chunk outer-product sums ----------------
__global__ __launch_bounds__(256) void chunk_sum(
  const float* __restrict__ Kk, const float* __restrict__ Vv,
  const float* __restrict__ CF, float* __restrict__ CS)
{
  int bh = blockIdx.x, c = blockIdx.y;
  int b = bh >> 4, h = bh & 15;
  __shared__ float k_s[64][65];
  __shared__ float v_s[64][65];
  __shared__ float cf_s[64];
  int tid = threadIdx.x;
  int row0 = b*L_ + c*CHUNK;
  const float* kp = Kk + (size_t)row0*D_ + h*64;
  const float* vp = Vv + (size_t)row0*D_ + h*64;
  #pragma unroll
  for (int t = 0; t < 16; ++t) {
    int idx = tid + t*256;
    int j = idx >> 6, d = idx & 63;
    k_s[j][d] = kp[(size_t)j*D_ + d];
    v_s[j][d] = vp[(size_t)j*D_ + d];
  }
  if (CF && tid < 64) cf_s[tid] = CF[(size_t)bh*L_ + c*CHUNK + tid];
  __syncthreads();
  int w = tid >> 6, ln = tid & 63;
  float S[16] = {};
  for (int j = 0; j < 64; ++j) {
    float cv = v_s[j][ln];
    if (CF) cv *= cf_s[j];
    #pragma unroll
    for (int i = 0; i < 16; ++i) S[i] += k_s[j][w*16+i] * cv;
  }
  float* out = CS + ((size_t)bh*NCH + c)*4096;
  #pragma unroll
  for (int i = 0; i < 16; ++i) out[(w*16+i)*64 + ln] = S[i];
}

// ---------------- exclusive prefix over chunk states ----------------
__global__ __launch_bounds__(256) void scan_chunks(float* __restrict__ CS)
{
  int bh = blockIdx.x;
  float run[16] = {};
  float* base = CS + (size_t)bh*NCH*4096;
  for (int c = 0; c < NCH; ++c) {
    float* p = base + c*4096;
    #pragma unroll
    for (int k = 0; k < 16; ++k) {
      int e = k*256 + threadIdx.x;
      float cur = p[e];
      p[e] = run[k];
      run[k] += cur;
    }
  }
}

// ---------------- AR O1 per chunk + fused E = x[t+1]-O1[t] ----------------
__global__ __launch_bounds__(256) void ar_o1(
  const float* __restrict__ Q, const float* __restrict__ Kk,
  const float* __restrict__ Vv, const float* __restrict__ CF,
  const float* __restrict__ GC, const float* __restrict__ CS,
  float* __restrict__ O1, float* __restrict__ E)
{
  int bh = blockIdx.x, c = blockIdx.y;
  int b = bh >> 4, h = bh & 15;
  __shared__ float q_s[64][65];
  __shared__ float k_s[64][65];   // reused to hold P after stage 1
  __shared__ float v_s[64][65];
  __shared__ float sc_s[64][65];
  __shared__ float cf_s[64], gc_s[64];
  int tid = threadIdx.x;
  int row0 = b*L_ + c*CHUNK;
  const float* qp = Q  + (size_t)row0*D_ + h*64;
  const float* kp = Kk + (size_t)row0*D_ + h*64;
  const float* vp = Vv + (size_t)row0*D_ + h*64;
  const float* scp = CS + ((size_t)bh*NCH + c)*4096;
  #pragma unroll
  for (int t = 0; t < 16; ++t) {
    int idx = tid + t*256;
    int j = idx >> 6, d = idx & 63;
    q_s[j][d]  = qp[(size_t)j*D_ + d];
    k_s[j][d]  = kp[(size_t)j*D_ + d];
    v_s[j][d]  = vp[(size_t)j*D_ + d];
    sc_s[j][d] = scp[idx];
  }
  if (tid < 64) {
    cf_s[tid] = CF[(size_t)bh*L_ + c*CHUNK + tid];
    gc_s[tid] = GC[(size_t)bh*L_ + c*CHUNK + tid];
  }
  __syncthreads();
  int w = tid >> 6, ln = tid & 63;
  float p[16];
  #pragma unroll
  for (int i = 0; i < 16; ++i) {
    int l = w*16 + i;
    float acc = 0.f;
    #pragma unroll 8
    for (int d = 0; d < 64; ++d) acc += q_s[l][d] * k_s[ln][d];
    p[i] = (ln <= l) ? acc * cf_s[ln] : 0.f;
  }
  __syncthreads();
  #pragma unroll
  for (int i = 0; i < 16; ++i) k_s[w*16+i][ln] = p[i];
  __syncthreads();
  #pragma unroll
  for (int i = 0; i < 16; ++i) {
    int l = w*16 + i;
    float acc = 0.f;
    #pragma unroll 8
    for (int d = 0; d < 64; ++d) acc += q_s[l][d] * sc_s[d][ln];
    #pragma unroll 8
    for (int j = 0; j < 64; ++j) acc += k_s[l][j] * v_s[j][ln];
    float o1 = gc_s[l] * acc;
    O1[(size_t)(row0 + l)*D_ + h*64 + ln] = o1;
    // fused E: E[t] = x[t+1] - O1[t], 0 at t = L-1
    float ev = 0.f;
    if (c*CHUNK + l < L_-1)
      ev = Vv[(size_t)(row0 + l + 1)*D_ + h*64 + ln] - o1;
    E[(size_t)(row0 + l)*D_ + h*64 + ln] = ev;
  }
}

// ---------------- MA O2 per chunk, added in place ----------------
__global__ __launch_bounds__(256) void ma_o2(
  const float* __restrict__ Q, const float* __restrict__ K2,
  const float* __restrict__ E, const float* __restrict__ CS,
  float* __restrict__ O1)
{
  int bh = blockIdx.x, c = blockIdx.y;
  int b = bh >> 4, h = bh & 15;
  __shared__ float q_s[64][65];   // q2
  __shared__ float k_s[64][65];   // k2, reused for P
  __shared__ float v_s[64][65];   // E
  __shared__ float sc_s[64][65];  // T carry
  int tid = threadIdx.x;
  int row0 = b*L_ + c*CHUNK;
  const float* qp = Q  + (size_t)row0*D_ + h*64;
  const float* kp = K2 + (size_t)row0*D_ + h*64;
  const float* vp = E  + (size_t)row0*D_ + h*64;
  const float* scp = CS + ((size_t)bh*NCH + c)*4096;
  #pragma unroll
  for (int t = 0; t < 16; ++t) {
    int idx = tid + t*256;
    int j = idx >> 6, d = idx & 63;
    float qv = qp[(size_t)j*D_ + d];
    q_s[j][d]  = (qv > 0.f ? 0.02f*qv : qv) * 0.125f;   // ma_q_activation
    k_s[j][d]  = kp[(size_t)j*D_ + d];
    v_s[j][d]  = vp[(size_t)j*D_ + d];
    sc_s[j][d] = scp[idx];
  }
  __syncthreads();
  int w = tid >> 6, ln = tid & 63;
  float p[16];
  #pragma unroll
  for (int i = 0; i < 16; ++i) {
    int l = w*16 + i;
    float acc = 0.f;
    #pragma unroll 8
    for (int d = 0; d < 64; ++d) acc += q_s[l][d] * k_s[ln][d];
    p[i] = (ln <= l) ? acc : 0.f;
  }
  __syncthreads();
  #pragma unroll
  for (int i = 0; i < 16; ++i) k_s[w*16+i][ln] = p[i];
  __syncthreads();
  #pragma unroll
  for (int i = 0; i < 16; ++i) {
    int l = w*16 + i;
    if (c*CHUNK + l < L_-1) {
      float acc = 0.f;
      #pragma unroll 8
      for (int d = 0; d < 64; ++d) acc += q_s[l][d] * sc_s[d][ln];
      #pragma unroll 8
      for (int j = 0; j < 64; ++j) acc += k_s[l][j] * v_s[j][ln];
      O1[(size_t)(row0 + l + 1)*D_ + h*64 + ln] += acc;
    }
  }
}

extern "C" void kernel_launch(void* const* d_in, const int* in_sizes, int n_in,
                              void* d_out, int out_size, void* d_ws, size_t ws_size,
                              hipStream_t stream) {
  const float* x  = (const float*)d_in[0];
  const float* Wq = (const float*)d_in[1];
  const float* bq = (const float*)d_in[2];
  const float* Wk1= (const float*)d_in[3];
  const float* bk1= (const float*)d_in[4];
  const float* Wk2= (const float*)d_in[5];
  const float* bk2= (const float*)d_in[6];
  const float* Wg = (const float*)d_in[7];
  const float* bg = (const float*)d_in[8];
  const float* Ws = (const float*)d_in[9];
  const float* bs = (const float*)d_in[10];
  const float* Wp = (const float*)d_in[11];
  const float* bp = (const float*)d_in[12];
  float* out = (float*)d_out;

  float* ws = (float*)d_ws;
  size_t MD = (size_t)M_*D_;
  float* Qb  = ws;                 // Q projection
  float* Kb  = Qb  + MD;           // K1 projection
  float* K2b = Kb  + MD;           // sigmoid(K2 projection)
  float* O1b = K2b + MD;           // O1, then O1+O2 in place
  float* Eb  = O1b + MD;           // MA residuals
  float* CSb = Eb  + MD;           // chunk states: 32*16*4096
  float* GLb = CSb + (size_t)32*NCH*4096;
  float* RRb = GLb + (size_t)M_*H_;
  float* GCb = RRb + (size_t)M_*H_;
  float* CFb = GCb + (size_t)32*L_;
  unsigned short* Xbf  = (unsigned short*)(CFb + (size_t)32*L_);
  unsigned short* Wt0  = Xbf + MD;          // Wq^T bf16 [N][K]
  unsigned short* Wt1  = Wt0 + MD/2;        // (1024*1024)
  unsigned short* Wt2  = Wt1 + MD/2;
  unsigned short* Wt3  = Wt2 + MD/2;
  unsigned short* O1bf = Wt3 + MD/2;

  // convert inputs to bf16
  f32_to_bf16<<<2048, 256, 0, stream>>>(x, Xbf, (int)(MD/4));
  dim3 gt(16, 16, 4);
  convert_wt<<<gt, 256, 0, stream>>>(Wq, Wk1, Wk2, Wp, Wt0, Wt1, Wt2, Wt3);

  // 3 fused projections via MFMA
  dim3 gg(M_/128, D_/64, 3);
  gemm3<<<gg, 256, 0, stream>>>(Xbf, Wt0, Wt1, Wt2, bq, bk1, bk2, Qb, Kb, K2b);

  scalars_kernel<<<(M_*H_)/4, 256, 0, stream>>>(x, Kb, Wg, bg, Ws, bs, GLb, RRb);
  gl_scan<<<8, 256, 0, stream>>>(GLb, RRb, GCb, CFb);

  // AR branch
  dim3 gc(32, NCH);
  chunk_sum<<<gc, 256, 0, stream>>>(Kb, x, CFb, CSb);
  scan_chunks<<<32, 256, 0, stream>>>(CSb);
  ar_o1<<<gc, 256, 0, stream>>>(Qb, Kb, x, CFb, GCb, CSb, O1b, Eb);

  // MA branch
  chunk_sum<<<gc, 256, 0, stream>>>(K2b, Eb, nullptr, CSb);
  scan_chunks<<<32, 256, 0, stream>>>(CSb);
  ma_o2<<<gc, 256, 0, stream>>>(Qb, K2b, Eb, CSb, O1b);

  // output projection via MFMA
  f32_to_bf16<<<2048, 256, 0, stream>>>(O1b, O1bf, (int)(MD/4));
  dim3 go(M_/128, D_/64);
  gemm1<<<go, 256, 0, stream>>>(O1bf, Wt3, bp, out);
}

// Round 5
// 201.556 us; speedup vs baseline: 6.1672x; 1.4708x over previous
//
#include <hip/hip_runtime.h>
#include <hip/hip_bf16.h>
#include <math.h>

#define B_  2
#define L_  1024
#define D_  1024
#define H_  16
#define DH_ 64
#define M_  (B_*L_)   // 2048
#define CHUNK 64
#define NCH (L_/CHUNK)   // 16
#define PT 72   // bf16 LDS tile pad (shorts): rows 144B, 16B-aligned
#define PS 76   // f32 LDS out-stage pad (floats): rows 304B, 16B-aligned

#define KSCALE (0.02f/32.0f)   // /sqrt(D) * 0.02

using bf16x8 = __attribute__((ext_vector_type(8))) short;
using f32x4  = __attribute__((ext_vector_type(4))) float;

__device__ __forceinline__ unsigned short bf16r(float f){
  union{float f; unsigned int u;} x; x.f = f;
  unsigned int r = x.u + 0x7FFF + ((x.u>>16)&1);
  return (unsigned short)(r>>16);
}
__device__ __forceinline__ float bf2f(unsigned short u){
  union{unsigned int u; float f;} x; x.u = ((unsigned int)u)<<16; return x.f;
}

// ---------------- fp32 -> bf16 ----------------
__global__ __launch_bounds__(256) void f32_to_bf16(
  const float* __restrict__ src, unsigned short* __restrict__ dst, int n4)
{
  int i = blockIdx.x*256 + threadIdx.x;
  int stride = gridDim.x*256;
  for (; i < n4; i += stride){
    float4 v = ((const float4*)src)[i];
    ushort4 o;
    o.x = bf16r(v.x); o.y = bf16r(v.y); o.z = bf16r(v.z); o.w = bf16r(v.w);
    ((ushort4*)dst)[i] = o;
  }
}

// ---------------- W fp32 [K][N] -> Wt bf16 [N][K] (4 matrices) ----------------
__global__ __launch_bounds__(256) void convert_wt(
  const float* __restrict__ W0, const float* __restrict__ W1,
  const float* __restrict__ W2, const float* __restrict__ W3,
  unsigned short* __restrict__ T0, unsigned short* __restrict__ T1,
  unsigned short* __restrict__ T2, unsigned short* __restrict__ T3)
{
  int which = blockIdx.z;
  const float* W = which==0?W0: which==1?W1: which==2?W2: W3;
  unsigned short* T = which==0?T0: which==1?T1: which==2?T2: T3;
  __shared__ float tile[64][65];
  int kBase = blockIdx.x*64, nBase = blockIdx.y*64;
  #pragma unroll
  for (int i=0;i<16;i++){
    int idx = threadIdx.x + i*256;
    int r = idx>>6, c = idx&63;
    tile[r][c] = W[(size_t)(kBase+r)*D_ + nBase+c];
  }
  __syncthreads();
  #pragma unroll
  for (int i=0;i<16;i++){
    int idx = threadIdx.x + i*256;
    int n = idx>>6, k = idx&63;
    T[(size_t)(nBase+n)*D_ + kBase+k] = bf16r(tile[k][n]);
  }
}

// ---------------- bf16 MFMA GEMM core ----------------
__device__ __forceinline__ void gemm_core(
    const unsigned short* __restrict__ A, const unsigned short* __restrict__ Bt,
    const float* __restrict__ bias, float* __restrict__ C,
    unsigned short* __restrict__ Cbf, int epi,
    int rowBase, int colBase)
{
  __shared__ __align__(16) unsigned short As[128*32];
  __shared__ __align__(16) unsigned short Bs[64*32];
  int tid = threadIdx.x, w = tid>>6, l = tid&63;
  int lr = l&15, g4 = l>>4;
  f32x4 acc[2][4];
  #pragma unroll
  for (int mi=0;mi<2;mi++)
    #pragma unroll
    for (int ni=0;ni<4;ni++)
      acc[mi][ni] = (f32x4){0.f,0.f,0.f,0.f};

  for (int k0 = 0; k0 < D_; k0 += 32) {
    #pragma unroll
    for (int i=0;i<2;i++){
      int F = (w*2+i)*64 + l;
      int r = F>>2, c16 = F&3;
      int sc = c16 ^ ((r>>1)&3);
      const unsigned short* g = A + (size_t)(rowBase+r)*D_ + k0 + sc*8;
      __builtin_amdgcn_global_load_lds(
        (const __attribute__((address_space(1))) void*)g,
        (__attribute__((address_space(3))) void*)(As + (size_t)(w*2+i)*512), 16, 0, 0);
    }
    {
      int F = w*64 + l;
      int r = F>>2, c16 = F&3;
      int sc = c16 ^ ((r>>1)&3);
      const unsigned short* g = Bt + (size_t)(colBase+r)*D_ + k0 + sc*8;
      __builtin_amdgcn_global_load_lds(
        (const __attribute__((address_space(1))) void*)g,
        (__attribute__((address_space(3))) void*)(Bs + (size_t)w*512), 16, 0, 0);
    }
    __syncthreads();
    bf16x8 af[2], bfr[4];
    #pragma unroll
    for (int mi=0;mi<2;mi++){
      int row = w*32 + mi*16 + lr;
      af[mi] = *(const bf16x8*)(As + row*32 + ((g4 ^ ((row>>1)&3))*8));
    }
    #pragma unroll
    for (int ni=0;ni<4;ni++){
      int n = ni*16 + lr;
      bfr[ni] = *(const bf16x8*)(Bs + n*32 + ((g4 ^ ((n>>1)&3))*8));
    }
    #pragma unroll
    for (int mi=0;mi<2;mi++)
      #pragma unroll
      for (int ni=0;ni<4;ni++)
        acc[mi][ni] = __builtin_amdgcn_mfma_f32_16x16x32_bf16(af[mi], bfr[ni], acc[mi][ni], 0,0,0);
    __syncthreads();
  }

  #pragma unroll
  for (int mi=0;mi<2;mi++){
    #pragma unroll
    for (int ni=0;ni<4;ni++){
      int col = colBase + ni*16 + lr;
      float bv = bias[col];
      #pragma unroll
      for (int r=0;r<4;r++){
        int row = rowBase + w*32 + mi*16 + g4*4 + r;
        float v = acc[mi][ni][r] + bv;
        if (epi) v = 1.f/(1.f + expf(-v*KSCALE));
        C[(size_t)row*D_ + col] = v;
        if (Cbf) Cbf[(size_t)row*D_ + col] = bf16r(v);
      }
    }
  }
}

// 3 projections in one launch; dual fp32+bf16 outputs
__global__ __launch_bounds__(256) void gemm3(
  const unsigned short* __restrict__ A,
  const unsigned short* __restrict__ T0, const unsigned short* __restrict__ T1,
  const unsigned short* __restrict__ T2,
  const float* __restrict__ b0, const float* __restrict__ b1, const float* __restrict__ b2,
  float* __restrict__ C0, float* __restrict__ C1, float* __restrict__ C2,
  unsigned short* __restrict__ F0, unsigned short* __restrict__ F1,
  unsigned short* __restrict__ F2)
{
  int z = blockIdx.z;
  const unsigned short* Bt = z==0?T0: z==1?T1: T2;
  const float* bias = z==0?b0: z==1?b1: b2;
  float* C = z==0?C0: z==1?C1: C2;
  unsigned short* F = z==0?F0: z==1?F1: F2;
  gemm_core(A, Bt, bias, C, F, z==2 ? 1 : 0, blockIdx.x*128, blockIdx.y*64);
}

__global__ __launch_bounds__(256) void gemm1(
  const unsigned short* __restrict__ A, const unsigned short* __restrict__ Bt,
  const float* __restrict__ bias, float* __restrict__ C)
{
  gemm_core(A, Bt, bias, C, nullptr, 0, blockIdx.x*128, blockIdx.y*64);
}

// ---------------- per-(b,l,h) scalar gates ----------------
__global__ __launch_bounds__(256) void scalars_kernel(
  const float* __restrict__ X, const float* __restrict__ K,
  const float* __restrict__ Wg, const float* __restrict__ bg,
  const float* __restrict__ Ws, const float* __restrict__ bs,
  float* __restrict__ GL, float* __restrict__ RR)
{
  int item = blockIdx.x * 4 + (threadIdx.x >> 6);
  int ln = threadIdx.x & 63;
  int row = item >> 4;
  int h = item & 15;
  float xv = X[(size_t)row*D_ + h*64 + ln];
  float kv = K[(size_t)row*D_ + h*64 + ln];
  float gdot = xv * Wg[ln];
  float rdot = kv * Ws[ln];
  #pragma unroll
  for (int off = 32; off; off >>= 1) {
    gdot += __shfl_xor(gdot, off);
    rdot += __shfl_xor(rdot, off);
  }
  if (ln == 0) {
    float glogit = gdot + bg[0];
    float sg = 1.f/(1.f+expf(-glogit));
    sg = fmaxf(sg, 1e-6f);
    GL[item] = logf(sg);
    float rlogit = rdot + bs[0];
    RR[item] = rlogit / (1.f + expf(-rlogit));
  }
}

// ---------------- gate prefix scan ----------------
__global__ __launch_bounds__(256) void gl_scan(
  const float* __restrict__ GL, const float* __restrict__ RR,
  float* __restrict__ GC, float* __restrict__ CF)
{
  int bh = blockIdx.x * 4 + (threadIdx.x >> 6);
  int b = bh >> 4, h = bh & 15;
  int ln = threadIdx.x & 63;
  float carry = 0.f;
  for (int it = 0; it < 16; ++it) {
    int l = it*64 + ln;
    float x = GL[((size_t)(b*L_ + l))*H_ + h];
    #pragma unroll
    for (int off = 1; off < 64; off <<= 1) {
      float t = __shfl_up(x, off);
      if (ln >= off) x += t;
    }
    float tot = __shfl(x, 63);
    float cum = carry + x;
    carry += tot;
    float lc = fminf(fmaxf(cum, -30.f), 30.f);
    float gc = expf(lc) + 1e-6f;
    GC[(size_t)bh*L_ + l] = gc;
    CF[(size_t)bh*L_ + l] = RR[((size_t)(b*L_ + l))*H_ + h] / gc;
  }
}

// ---------------- AR chunk sum (MFMA): CS_T[e][d] = sum_j cf_j*V[j][e]*K[j][d] ----------------
__global__ __launch_bounds__(256) void ar_chunk_sum(
  const unsigned short* __restrict__ Kbf, const unsigned short* __restrict__ Xbf,
  const float* __restrict__ CF, float* __restrict__ CS)
{
  int bh = blockIdx.x, c = blockIdx.y;
  int b = bh >> 4, h = bh & 15;
  int row0 = b*L_ + c*CHUNK;
  __shared__ __align__(16) unsigned short kt_t[64*PT];   // K^T [d][j]
  __shared__ __align__(16) unsigned short cv_t[64*PT];   // (cf*V)^T [e][j]
  __shared__ __align__(16) float uni[64*PS];
  __shared__ float cf_s[64];
  int tid = threadIdx.x;
  if (tid < 64) cf_s[tid] = CF[(size_t)bh*L_ + c*CHUNK + tid];
  __syncthreads();
  const unsigned short* kg = Kbf + (size_t)row0*D_ + h*64;
  const unsigned short* vg = Xbf + (size_t)row0*D_ + h*64;
  #pragma unroll
  for (int t=0;t<16;t++){
    int idx = tid + t*256;
    int j = idx>>6, d = idx&63;
    kt_t[d*PT + j] = kg[(size_t)j*D_ + d];
    cv_t[d*PT + j] = bf16r(bf2f(vg[(size_t)j*D_ + d]) * cf_s[j]);
  }
  __syncthreads();
  int w = tid>>6, l = tid&63, lr = l&15, g4 = l>>4;
  f32x4 acc[4];
  #pragma unroll
  for (int ni=0;ni<4;ni++) acc[ni] = (f32x4){0.f,0.f,0.f,0.f};
  #pragma unroll
  for (int kk=0;kk<2;kk++){
    bf16x8 a = *(const bf16x8*)&cv_t[(w*16+lr)*PT + kk*32 + g4*8];
    #pragma unroll
    for (int ni=0;ni<4;ni++){
      bf16x8 bb = *(const bf16x8*)&kt_t[(ni*16+lr)*PT + kk*32 + g4*8];
      acc[ni] = __builtin_amdgcn_mfma_f32_16x16x32_bf16(a, bb, acc[ni], 0,0,0);
    }
  }
  #pragma unroll
  for (int ni=0;ni<4;ni++)
    #pragma unroll
    for (int r=0;r<4;r++)
      uni[(w*16+g4*4+r)*PS + ni*16+lr] = acc[ni][r];
  __syncthreads();
  float* out = CS + ((size_t)bh*NCH + c)*4096;
  #pragma unroll
  for (int t=0;t<4;t++){
    int idx = tid + t*256;
    int r = idx>>4, s = idx&15;
    *(float4*)&out[r*64 + s*4] = *(float4*)&uni[r*PS + s*4];
  }
}

// ---------------- MA chunk sum (MFMA): CS_T[e][d] = sum_j E[j][e]*k2[j][d] ----------------
__global__ __launch_bounds__(256) void ma_chunk_sum(
  const unsigned short* __restrict__ K2bf, const float* __restrict__ X,
  const float* __restrict__ O1, float* __restrict__ CS)
{
  int bh = blockIdx.x, c = blockIdx.y;
  int b = bh >> 4, h = bh & 15;
  int row0 = b*L_ + c*CHUNK;
  __shared__ __align__(16) unsigned short kt_t[64*PT];   // k2^T [d][j]
  __shared__ __align__(16) unsigned short et_t[64*PT];   // E^T [e][j]
  __shared__ __align__(16) float uni[64*PS];
  int tid = threadIdx.x;
  const unsigned short* kg = K2bf + (size_t)row0*D_ + h*64;
  #pragma unroll
  for (int t=0;t<16;t++){
    int idx = tid + t*256;
    int j = idx>>6, d = idx&63;
    kt_t[d*PT + j] = kg[(size_t)j*D_ + d];
    float ev = 0.f;
    if (c*CHUNK + j < L_-1)
      ev = X[(size_t)(row0+j+1)*D_ + h*64 + d] - O1[(size_t)(row0+j)*D_ + h*64 + d];
    et_t[d*PT + j] = bf16r(ev);
  }
  __syncthreads();
  int w = tid>>6, l = tid&63, lr = l&15, g4 = l>>4;
  f32x4 acc[4];
  #pragma unroll
  for (int ni=0;ni<4;ni++) acc[ni] = (f32x4){0.f,0.f,0.f,0.f};
  #pragma unroll
  for (int kk=0;kk<2;kk++){
    bf16x8 a = *(const bf16x8*)&et_t[(w*16+lr)*PT + kk*32 + g4*8];
    #pragma unroll
    for (int ni=0;ni<4;ni++){
      bf16x8 bb = *(const bf16x8*)&kt_t[(ni*16+lr)*PT + kk*32 + g4*8];
      acc[ni] = __builtin_amdgcn_mfma_f32_16x16x32_bf16(a, bb, acc[ni], 0,0,0);
    }
  }
  #pragma unroll
  for (int ni=0;ni<4;ni++)
    #pragma unroll
    for (int r=0;r<4;r++)
      uni[(w*16+g4*4+r)*PS + ni*16+lr] = acc[ni][r];
  __syncthreads();
  float* out = CS + ((size_t)bh*NCH + c)*4096;
  #pragma unroll
  for (int t=0;t<4;t++){
    int idx = tid + t*256;
    int r = idx>>4, s = idx&15;
    *(float4*)&out[r*64 + s*4] = *(float4*)&uni[r*PS + s*4];
  }
}

// ---------------- exclusive prefix over chunk states (parallel) ----------------
__global__ __launch_bounds__(256) void scan_chunks_par(float* __restrict__ CS)
{
  int bh = blockIdx.x;
  int idx = blockIdx.y*256 + threadIdx.x;
  float run = 0.f;
  float* base = CS + (size_t)bh*NCH*4096 + idx;
  #pragma unroll
  for (int c = 0; c < NCH; ++c) {
    float cur = base[c*4096];
    base[c*4096] = run;
    run += cur;
  }
}

// ---------------- AR O1 per chunk (MFMA) ----------------
__global__ __launch_bounds__(256) void ar_o1_mfma(
  const unsigned short* __restrict__ Qbf, const unsigned short* __restrict__ Kbf,
  const unsigned short* __restrict__ Xbf, const float* __restrict__ CF,
  const float* __restrict__ GC, const float* __restrict__ CS,
  float* __restrict__ O1)
{
  int bh = blockIdx.x, c = blockIdx.y;
  int b = bh >> 4, h = bh & 15;
  int row0 = b*L_ + c*CHUNK;
  __shared__ __align__(16) unsigned short q_t[64*PT];
  __shared__ __align__(16) unsigned short k_t[64*PT];
  __shared__ __align__(16) unsigned short vt_t[64*PT];   // V^T [e][j]
  __shared__ __align__(16) unsigned short st_t[64*PT];   // Sc^T [e][d]
  __shared__ __align__(16) float uni[64*PS];             // P (low half) / out stage
  unsigned short* p_t = (unsigned short*)uni;
  __shared__ float cf_s[64], gc_s[64];
  int tid = threadIdx.x;
  if (tid < 64) {
    cf_s[tid] = CF[(size_t)bh*L_ + c*CHUNK + tid];
    gc_s[tid] = GC[(size_t)bh*L_ + c*CHUNK + tid];
  }
  const unsigned short* qg = Qbf + (size_t)row0*D_ + h*64;
  const unsigned short* kg = Kbf + (size_t)row0*D_ + h*64;
  const unsigned short* vg = Xbf + (size_t)row0*D_ + h*64;
  const float* sg = CS + ((size_t)bh*NCH + c)*4096;
  #pragma unroll
  for (int t=0;t<2;t++){
    int idx = tid + t*256;
    int j = idx>>3, s = idx&7;
    *(uint4*)&q_t[j*PT + s*8] = *(const uint4*)&qg[(size_t)j*D_ + s*8];
    *(uint4*)&k_t[j*PT + s*8] = *(const uint4*)&kg[(size_t)j*D_ + s*8];
  }
  #pragma unroll
  for (int t=0;t<16;t++){
    int idx = tid + t*256;
    int j = idx>>6, d = idx&63;
    vt_t[d*PT + j] = vg[(size_t)j*D_ + d];
    st_t[j*PT + d] = bf16r(sg[idx]);   // natural [e][d], idx = e*64+d
  }
  __syncthreads();
  int w = tid>>6, l = tid&63, lr = l&15, g4 = l>>4;
  // mfma1: P = causal(Q @ K^T) * cf
  f32x4 acc[4];
  #pragma unroll
  for (int ni=0;ni<4;ni++) acc[ni] = (f32x4){0.f,0.f,0.f,0.f};
  #pragma unroll
  for (int kk=0;kk<2;kk++){
    bf16x8 a = *(const bf16x8*)&q_t[(w*16+lr)*PT + kk*32 + g4*8];
    #pragma unroll
    for (int ni=0;ni<4;ni++){
      bf16x8 bb = *(const bf16x8*)&k_t[(ni*16+lr)*PT + kk*32 + g4*8];
      acc[ni] = __builtin_amdgcn_mfma_f32_16x16x32_bf16(a, bb, acc[ni], 0,0,0);
    }
  }
  #pragma unroll
  for (int ni=0;ni<4;ni++){
    int j = ni*16 + lr;
    float cf = cf_s[j];
    #pragma unroll
    for (int r=0;r<4;r++){
      int row = w*16 + g4*4 + r;
      float v = (j <= row) ? acc[ni][r]*cf : 0.f;
      p_t[row*PT + j] = bf16r(v);
    }
  }
  __syncthreads();
  // mfma2: O1 = P@V + Q@Sc^T
  #pragma unroll
  for (int ni=0;ni<4;ni++) acc[ni] = (f32x4){0.f,0.f,0.f,0.f};
  #pragma unroll
  for (int kk=0;kk<2;kk++){
    bf16x8 ap = *(const bf16x8*)&p_t[(w*16+lr)*PT + kk*32 + g4*8];
    bf16x8 aq = *(const bf16x8*)&q_t[(w*16+lr)*PT + kk*32 + g4*8];
    #pragma unroll
    for (int ni=0;ni<4;ni++){
      bf16x8 bv = *(const bf16x8*)&vt_t[(ni*16+lr)*PT + kk*32 + g4*8];
      bf16x8 bs = *(const bf16x8*)&st_t[(ni*16+lr)*PT + kk*32 + g4*8];
      acc[ni] = __builtin_amdgcn_mfma_f32_16x16x32_bf16(ap, bv, acc[ni], 0,0,0);
      acc[ni] = __builtin_amdgcn_mfma_f32_16x16x32_bf16(aq, bs, acc[ni], 0,0,0);
    }
  }
  __syncthreads();   // all waves done with p_t before uni overwrite
  #pragma unroll
  for (int ni=0;ni<4;ni++)
    #pragma unroll
    for (int r=0;r<4;r++){
      int row = w*16 + g4*4 + r;
      uni[row*PS + ni*16 + lr] = gc_s[row]*acc[ni][r];
    }
  __syncthreads();
  #pragma unroll
  for (int t=0;t<4;t++){
    int idx = tid + t*256;
    int r = idx>>4, s = idx&15;
    *(float4*)&O1[(size_t)(row0+r)*D_ + h*64 + s*4] = *(float4*)&uni[r*PS + s*4];
  }
}

// ---------------- MA O2 per chunk (MFMA), added in place ----------------
__global__ __launch_bounds__(256) void ma_o2_mfma(
  const unsigned short* __restrict__ Qbf, const unsigned short* __restrict__ K2bf,
  const float* __restrict__ X, const float* __restrict__ CS,
  float* __restrict__ O1)
{
  int bh = blockIdx.x, c = blockIdx.y;
  int b = bh >> 4, h = bh & 15;
  int row0 = b*L_ + c*CHUNK;
  __shared__ __align__(16) unsigned short q_t[64*PT];    // q2 [t][d]
  __shared__ __align__(16) unsigned short k_t[64*PT];    // k2 [j][d]
  __shared__ __align__(16) unsigned short et_t[64*PT];   // E^T [e][j]
  __shared__ __align__(16) unsigned short tt_t[64*PT];   // Tc^T [e][d]
  __shared__ __align__(16) float uni[64*PS];
  unsigned short* p_t = (unsigned short*)uni;
  int tid = threadIdx.x;
  const unsigned short* qg = Qbf  + (size_t)row0*D_ + h*64;
  const unsigned short* kg = K2bf + (size_t)row0*D_ + h*64;
  const float* sg = CS + ((size_t)bh*NCH + c)*4096;
  #pragma unroll
  for (int t=0;t<2;t++){
    int idx = tid + t*256;
    int j = idx>>3, s = idx&7;
    *(uint4*)&k_t[j*PT + s*8] = *(const uint4*)&kg[(size_t)j*D_ + s*8];
  }
  #pragma unroll
  for (int t=0;t<16;t++){
    int idx = tid + t*256;
    int j = idx>>6, d = idx&63;
    float qv = bf2f(qg[(size_t)j*D_ + d]);
    q_t[j*PT + d] = bf16r((qv > 0.f ? 0.02f*qv : qv) * 0.125f);
    float ev = 0.f;
    if (c*CHUNK + j < L_-1)
      ev = X[(size_t)(row0+j+1)*D_ + h*64 + d] - O1[(size_t)(row0+j)*D_ + h*64 + d];
    et_t[d*PT + j] = bf16r(ev);
    tt_t[j*PT + d] = bf16r(sg[idx]);
  }
  __syncthreads();
  int w = tid>>6, l = tid&63, lr = l&15, g4 = l>>4;
  f32x4 acc[4];
  #pragma unroll
  for (int ni=0;ni<4;ni++) acc[ni] = (f32x4){0.f,0.f,0.f,0.f};
  #pragma unroll
  for (int kk=0;kk<2;kk++){
    bf16x8 a = *(const bf16x8*)&q_t[(w*16+lr)*PT + kk*32 + g4*8];
    #pragma unroll
    for (int ni=0;ni<4;ni++){
      bf16x8 bb = *(const bf16x8*)&k_t[(ni*16+lr)*PT + kk*32 + g4*8];
      acc[ni] = __builtin_amdgcn_mfma_f32_16x16x32_bf16(a, bb, acc[ni], 0,0,0);
    }
  }
  #pragma unroll
  for (int ni=0;ni<4;ni++){
    int j = ni*16 + lr;
    #pragma unroll
    for (int r=0;r<4;r++){
      int row = w*16 + g4*4 + r;
      float v = (j <= row) ? acc[ni][r] : 0.f;
      p_t[row*PT + j] = bf16r(v);
    }
  }
  __syncthreads();
  #pragma unroll
  for (int ni=0;ni<4;ni++) acc[ni] = (f32x4){0.f,0.f,0.f,0.f};
  #pragma unroll
  for (int kk=0;kk<2;kk++){
    bf16x8 ap = *(const bf16x8*)&p_t[(w*16+lr)*PT + kk*32 + g4*8];
    bf16x8 aq = *(const bf16x8*)&q_t[(w*16+lr)*PT + kk*32 + g4*8];
    #pragma unroll
    for (int ni=0;ni<4;ni++){
      bf16x8 be = *(const bf16x8*)&et_t[(ni*16+lr)*PT + kk*32 + g4*8];
      bf16x8 bt = *(const bf16x8*)&tt_t[(ni*16+lr)*PT + kk*32 + g4*8];
      acc[ni] = __builtin_amdgcn_mfma_f32_16x16x32_bf16(ap, be, acc[ni], 0,0,0);
      acc[ni] = __builtin_amdgcn_mfma_f32_16x16x32_bf16(aq, bt, acc[ni], 0,0,0);
    }
  }
  __syncthreads();
  #pragma unroll
  for (int ni=0;ni<4;ni++)
    #pragma unroll
    for (int r=0;r<4;r++){
      int row = w*16 + g4*4 + r;
      uni[row*PS + ni*16 + lr] = acc[ni][r];
    }
  __syncthreads();
  #pragma unroll
  for (int t=0;t<4;t++){
    int idx = tid + t*256;
    int r = idx>>4, s = idx&15;
    if (c*CHUNK + r < L_-1) {
      float4* gp = (float4*)&O1[(size_t)(row0+r+1)*D_ + h*64 + s*4];
      float4 gv = *gp;
      float4 uv = *(float4*)&uni[r*PS + s*4];
      gv.x += uv.x; gv.y += uv.y; gv.z += uv.z; gv.w += uv.w;
      *gp = gv;
    }
  }
}

extern "C" void kernel_launch(void* const* d_in, const int* in_sizes, int n_in,
                              void* d_out, int out_size, void* d_ws, size_t ws_size,
                              hipStream_t stream) {
  const float* x  = (const float*)d_in[0];
  const float* Wq = (const float*)d_in[1];
  const float* bq = (const float*)d_in[2];
  const float* Wk1= (const float*)d_in[3];
  const float* bk1= (const float*)d_in[4];
  const float* Wk2= (const float*)d_in[5];
  const float* bk2= (const float*)d_in[6];
  const float* Wg = (const float*)d_in[7];
  const float* bg = (const float*)d_in[8];
  const float* Ws = (const float*)d_in[9];
  const float* bs = (const float*)d_in[10];
  const float* Wp = (const float*)d_in[11];
  const float* bp = (const float*)d_in[12];
  float* out = (float*)d_out;

  float* ws = (float*)d_ws;
  size_t MD = (size_t)M_*D_;
  float* Qb  = ws;
  float* Kb  = Qb  + MD;
  float* K2b = Kb  + MD;
  float* O1b = K2b + MD;
  float* CSb = O1b + MD;                     // 32*16*4096 floats
  float* GLb = CSb + (size_t)32*NCH*4096;
  float* RRb = GLb + (size_t)M_*H_;
  float* GCb = RRb + (size_t)M_*H_;
  float* CFb = GCb + (size_t)32*L_;
  unsigned short* Xbf   = (unsigned short*)(CFb + (size_t)32*L_);
  unsigned short* Qbfs  = Xbf  + MD;
  unsigned short* Kbfs  = Qbfs + MD;
  unsigned short* K2bfs = Kbfs + MD;
  unsigned short* O1bf  = K2bfs+ MD;
  unsigned short* Wt0   = O1bf + MD;
  unsigned short* Wt1   = Wt0 + (size_t)D_*D_;
  unsigned short* Wt2   = Wt1 + (size_t)D_*D_;
  unsigned short* Wt3   = Wt2 + (size_t)D_*D_;

  f32_to_bf16<<<2048, 256, 0, stream>>>(x, Xbf, (int)(MD/4));
  dim3 gt(16, 16, 4);
  convert_wt<<<gt, 256, 0, stream>>>(Wq, Wk1, Wk2, Wp, Wt0, Wt1, Wt2, Wt3);

  dim3 gg(M_/128, D_/64, 3);
  gemm3<<<gg, 256, 0, stream>>>(Xbf, Wt0, Wt1, Wt2, bq, bk1, bk2,
                                Qb, Kb, K2b, Qbfs, Kbfs, K2bfs);

  scalars_kernel<<<(M_*H_)/4, 256, 0, stream>>>(x, Kb, Wg, bg, Ws, bs, GLb, RRb);
  gl_scan<<<8, 256, 0, stream>>>(GLb, RRb, GCb, CFb);

  dim3 gc(32, NCH);
  ar_chunk_sum<<<gc, 256, 0, stream>>>(Kbfs, Xbf, CFb, CSb);
  scan_chunks_par<<<gc, 256, 0, stream>>>(CSb);
  ar_o1_mfma<<<gc, 256, 0, stream>>>(Qbfs, Kbfs, Xbf, CFb, GCb, CSb, O1b);

  ma_chunk_sum<<<gc, 256, 0, stream>>>(K2bfs, x, O1b, CSb);
  scan_chunks_par<<<gc, 256, 0, stream>>>(CSb);
  ma_o2_mfma<<<gc, 256, 0, stream>>>(Qbfs, K2bfs, x, CSb, O1b);

  f32_to_bf16<<<2048, 256, 0, stream>>>(O1b, O1bf, (int)(MD/4));
  dim3 go(M_/128, D_/64);
  gemm1<<<go, 256, 0, stream>>>(O1bf, Wt3, bp, out);
}

// Round 7
// 199.636 us; speedup vs baseline: 6.2265x; 1.0096x over previous
//
#include <hip/hip_runtime.h>
#include <hip/hip_bf16.h>
#include <math.h>

#define B_  2
#define L_  1024
#define D_  1024
#define H_  16
#define DH_ 64
#define M_  (B_*L_)   // 2048
#define CHUNK 64
#define NCH (L_/CHUNK)   // 16
#define PT 72   // bf16 LDS tile pad (shorts): rows 144B, 16B-aligned
#define PS 76   // f32 LDS out-stage pad (floats): rows 304B, 16B-aligned

#define KSCALE (0.02f/32.0f)   // /sqrt(D) * 0.02

using bf16x8 = __attribute__((ext_vector_type(8))) short;
using f32x4  = __attribute__((ext_vector_type(4))) float;

__device__ __forceinline__ unsigned short bf16r(float f){
  union{float f; unsigned int u;} x; x.f = f;
  unsigned int r = x.u + 0x7FFF + ((x.u>>16)&1);
  return (unsigned short)(r>>16);
}
__device__ __forceinline__ float bf2f(unsigned short u){
  union{unsigned int u; float f;} x; x.u = ((unsigned int)u)<<16; return x.f;
}

// ---------------- fp32 -> bf16 ----------------
__global__ __launch_bounds__(256) void f32_to_bf16(
  const float* __restrict__ src, unsigned short* __restrict__ dst, int n4)
{
  int i = blockIdx.x*256 + threadIdx.x;
  int stride = gridDim.x*256;
  for (; i < n4; i += stride){
    float4 v = ((const float4*)src)[i];
    ushort4 o;
    o.x = bf16r(v.x); o.y = bf16r(v.y); o.z = bf16r(v.z); o.w = bf16r(v.w);
    ((ushort4*)dst)[i] = o;
  }
}

// ---------------- W fp32 [K][N] -> Wt bf16 [N][K] (4 matrices) ----------------
__global__ __launch_bounds__(256) void convert_wt(
  const float* __restrict__ W0, const float* __restrict__ W1,
  const float* __restrict__ W2, const float* __restrict__ W3,
  unsigned short* __restrict__ T0, unsigned short* __restrict__ T1,
  unsigned short* __restrict__ T2, unsigned short* __restrict__ T3)
{
  int which = blockIdx.z;
  const float* W = which==0?W0: which==1?W1: which==2?W2: W3;
  unsigned short* T = which==0?T0: which==1?T1: which==2?T2: T3;
  __shared__ float tile[64][65];
  int kBase = blockIdx.x*64, nBase = blockIdx.y*64;
  #pragma unroll
  for (int i=0;i<16;i++){
    int idx = threadIdx.x + i*256;
    int r = idx>>6, c = idx&63;
    tile[r][c] = W[(size_t)(kBase+r)*D_ + nBase+c];
  }
  __syncthreads();
  #pragma unroll
  for (int i=0;i<16;i++){
    int idx = threadIdx.x + i*256;
    int n = idx>>6, k = idx&63;
    T[(size_t)(nBase+n)*D_ + kBase+k] = bf16r(tile[k][n]);
  }
}

// ---------------- bf16 MFMA GEMM core ----------------
__device__ __forceinline__ void gemm_core(
    const unsigned short* __restrict__ A, const unsigned short* __restrict__ Bt,
    const float* __restrict__ bias, float* __restrict__ C,
    unsigned short* __restrict__ Cbf, int epi,
    int rowBase, int colBase)
{
  __shared__ __align__(16) unsigned short As[128*32];
  __shared__ __align__(16) unsigned short Bs[64*32];
  int tid = threadIdx.x, w = tid>>6, l = tid&63;
  int lr = l&15, g4 = l>>4;
  f32x4 acc[2][4];
  #pragma unroll
  for (int mi=0;mi<2;mi++)
    #pragma unroll
    for (int ni=0;ni<4;ni++)
      acc[mi][ni] = (f32x4){0.f,0.f,0.f,0.f};

  for (int k0 = 0; k0 < D_; k0 += 32) {
    #pragma unroll
    for (int i=0;i<2;i++){
      int F = (w*2+i)*64 + l;
      int r = F>>2, c16 = F&3;
      int sc = c16 ^ ((r>>1)&3);
      const unsigned short* g = A + (size_t)(rowBase+r)*D_ + k0 + sc*8;
      __builtin_amdgcn_global_load_lds(
        (const __attribute__((address_space(1))) void*)g,
        (__attribute__((address_space(3))) void*)(As + (size_t)(w*2+i)*512), 16, 0, 0);
    }
    {
      int F = w*64 + l;
      int r = F>>2, c16 = F&3;
      int sc = c16 ^ ((r>>1)&3);
      const unsigned short* g = Bt + (size_t)(colBase+r)*D_ + k0 + sc*8;
      __builtin_amdgcn_global_load_lds(
        (const __attribute__((address_space(1))) void*)g,
        (__attribute__((address_space(3))) void*)(Bs + (size_t)w*512), 16, 0, 0);
    }
    __syncthreads();
    bf16x8 af[2], bfr[4];
    #pragma unroll
    for (int mi=0;mi<2;mi++){
      int row = w*32 + mi*16 + lr;
      af[mi] = *(const bf16x8*)(As + row*32 + ((g4 ^ ((row>>1)&3))*8));
    }
    #pragma unroll
    for (int ni=0;ni<4;ni++){
      int n = ni*16 + lr;
      bfr[ni] = *(const bf16x8*)(Bs + n*32 + ((g4 ^ ((n>>1)&3))*8));
    }
    #pragma unroll
    for (int mi=0;mi<2;mi++)
      #pragma unroll
      for (int ni=0;ni<4;ni++)
        acc[mi][ni] = __builtin_amdgcn_mfma_f32_16x16x32_bf16(af[mi], bfr[ni], acc[mi][ni], 0,0,0);
    __syncthreads();
  }

  #pragma unroll
  for (int mi=0;mi<2;mi++){
    #pragma unroll
    for (int ni=0;ni<4;ni++){
      int col = colBase + ni*16 + lr;
      float bv = bias[col];
      #pragma unroll
      for (int r=0;r<4;r++){
        int row = rowBase + w*32 + mi*16 + g4*4 + r;
        float v = acc[mi][ni][r] + bv;
        if (epi) v = 1.f/(1.f + expf(-v*KSCALE));
        C[(size_t)row*D_ + col] = v;
        if (Cbf) Cbf[(size_t)row*D_ + col] = bf16r(v);
      }
    }
  }
}

__global__ __launch_bounds__(256) void gemm3(
  const unsigned short* __restrict__ A,
  const unsigned short* __restrict__ T0, const unsigned short* __restrict__ T1,
  const unsigned short* __restrict__ T2,
  const float* __restrict__ b0, const float* __restrict__ b1, const float* __restrict__ b2,
  float* __restrict__ C0, float* __restrict__ C1, float* __restrict__ C2,
  unsigned short* __restrict__ F0, unsigned short* __restrict__ F1,
  unsigned short* __restrict__ F2)
{
  int z = blockIdx.z;
  const unsigned short* Bt = z==0?T0: z==1?T1: T2;
  const float* bias = z==0?b0: z==1?b1: b2;
  float* C = z==0?C0: z==1?C1: C2;
  unsigned short* F = z==0?F0: z==1?F1: F2;
  gemm_core(A, Bt, bias, C, F, z==2 ? 1 : 0, blockIdx.x*128, blockIdx.y*64);
}

__global__ __launch_bounds__(256) void gemm1(
  const unsigned short* __restrict__ A, const unsigned short* __restrict__ Bt,
  const float* __restrict__ bias, float* __restrict__ C)
{
  gemm_core(A, Bt, bias, C, nullptr, 0, blockIdx.x*128, blockIdx.y*64);
}

// ---------------- per-(b,l,h) scalar gates ----------------
__global__ __launch_bounds__(256) void scalars_kernel(
  const float* __restrict__ X, const float* __restrict__ K,
  const float* __restrict__ Wg, const float* __restrict__ bg,
  const float* __restrict__ Ws, const float* __restrict__ bs,
  float* __restrict__ GL, float* __restrict__ RR)
{
  int item = blockIdx.x * 4 + (threadIdx.x >> 6);
  int ln = threadIdx.x & 63;
  int row = item >> 4;
  int h = item & 15;
  float xv = X[(size_t)row*D_ + h*64 + ln];
  float kv = K[(size_t)row*D_ + h*64 + ln];
  float gdot = xv * Wg[ln];
  float rdot = kv * Ws[ln];
  #pragma unroll
  for (int off = 32; off; off >>= 1) {
    gdot += __shfl_xor(gdot, off);
    rdot += __shfl_xor(rdot, off);
  }
  if (ln == 0) {
    float glogit = gdot + bg[0];
    float sg = 1.f/(1.f+expf(-glogit));
    sg = fmaxf(sg, 1e-6f);
    GL[item] = logf(sg);
    float rlogit = rdot + bs[0];
    RR[item] = rlogit / (1.f + expf(-rlogit));
  }
}

// ---------------- gate prefix scan ----------------
__global__ __launch_bounds__(256) void gl_scan(
  const float* __restrict__ GL, const float* __restrict__ RR,
  float* __restrict__ GC, float* __restrict__ CF)
{
  int bh = blockIdx.x * 4 + (threadIdx.x >> 6);
  int b = bh >> 4, h = bh & 15;
  int ln = threadIdx.x & 63;
  float carry = 0.f;
  for (int it = 0; it < 16; ++it) {
    int l = it*64 + ln;
    float x = GL[((size_t)(b*L_ + l))*H_ + h];
    #pragma unroll
    for (int off = 1; off < 64; off <<= 1) {
      float t = __shfl_up(x, off);
      if (ln >= off) x += t;
    }
    float tot = __shfl(x, 63);
    float cum = carry + x;
    carry += tot;
    float lc = fminf(fmaxf(cum, -30.f), 30.f);
    float gc = expf(lc) + 1e-6f;
    GC[(size_t)bh*L_ + l] = gc;
    CF[(size_t)bh*L_ + l] = RR[((size_t)(b*L_ + l))*H_ + h] / gc;
  }
}

// ---------------- AR chunk sum (MFMA): CS_T[e][d] = sum_j cf_j*V[j][e]*K[j][d] ----------------
__global__ __launch_bounds__(256) void ar_chunk_sum(
  const unsigned short* __restrict__ Kbf, const unsigned short* __restrict__ Xbf,
  const float* __restrict__ CF, float* __restrict__ CS)
{
  int bh = blockIdx.x, c = blockIdx.y;
  int b = bh >> 4, h = bh & 15;
  int row0 = b*L_ + c*CHUNK;
  __shared__ __align__(16) unsigned short kt_t[64*PT];   // K^T [d][j]
  __shared__ __align__(16) unsigned short cv_t[64*PT];   // (cf*V)^T [e][j]
  __shared__ __align__(16) float uni[64*PS];
  __shared__ float cf_s[64];
  int tid = threadIdx.x;
  if (tid < 64) cf_s[tid] = CF[(size_t)bh*L_ + c*CHUNK + tid];
  __syncthreads();
  const unsigned short* kg = Kbf + (size_t)row0*D_ + h*64;
  const unsigned short* vg = Xbf + (size_t)row0*D_ + h*64;
  #pragma unroll
  for (int t=0;t<16;t++){
    int idx = tid + t*256;
    int j = idx>>6, d = idx&63;
    kt_t[d*PT + j] = kg[(size_t)j*D_ + d];
    cv_t[d*PT + j] = bf16r(bf2f(vg[(size_t)j*D_ + d]) * cf_s[j]);
  }
  __syncthreads();
  int w = tid>>6, l = tid&63, lr = l&15, g4 = l>>4;
  f32x4 acc[4];
  #pragma unroll
  for (int ni=0;ni<4;ni++) acc[ni] = (f32x4){0.f,0.f,0.f,0.f};
  #pragma unroll
  for (int kk=0;kk<2;kk++){
    bf16x8 a = *(const bf16x8*)&cv_t[(w*16+lr)*PT + kk*32 + g4*8];
    #pragma unroll
    for (int ni=0;ni<4;ni++){
      bf16x8 bb = *(const bf16x8*)&kt_t[(ni*16+lr)*PT + kk*32 + g4*8];
      acc[ni] = __builtin_amdgcn_mfma_f32_16x16x32_bf16(a, bb, acc[ni], 0,0,0);
    }
  }
  #pragma unroll
  for (int ni=0;ni<4;ni++)
    #pragma unroll
    for (int r=0;r<4;r++)
      uni[(w*16+g4*4+r)*PS + ni*16+lr] = acc[ni][r];
  __syncthreads();
  float* out = CS + ((size_t)bh*NCH + c)*4096;
  #pragma unroll
  for (int t=0;t<4;t++){
    int idx = tid + t*256;
    int r = idx>>4, s = idx&15;
    *(float4*)&out[r*64 + s*4] = *(float4*)&uni[r*PS + s*4];
  }
}

// ---------------- MA chunk sum (MFMA): CS_T[e][d] = sum_j E[j][e]*k2[j][d] ----------------
__global__ __launch_bounds__(256) void ma_chunk_sum(
  const unsigned short* __restrict__ K2bf, const float* __restrict__ X,
  const float* __restrict__ O1, float* __restrict__ CS)
{
  int bh = blockIdx.x, c = blockIdx.y;
  int b = bh >> 4, h = bh & 15;
  int row0 = b*L_ + c*CHUNK;
  __shared__ __align__(16) unsigned short kt_t[64*PT];   // k2^T [d][j]
  __shared__ __align__(16) unsigned short et_t[64*PT];   // E^T [e][j]
  __shared__ __align__(16) float uni[64*PS];
  int tid = threadIdx.x;
  const unsigned short* kg = K2bf + (size_t)row0*D_ + h*64;
  #pragma unroll
  for (int t=0;t<16;t++){
    int idx = tid + t*256;
    int j = idx>>6, d = idx&63;
    kt_t[d*PT + j] = kg[(size_t)j*D_ + d];
    float ev = 0.f;
    if (c*CHUNK + j < L_-1)
      ev = X[(size_t)(row0+j+1)*D_ + h*64 + d] - O1[(size_t)(row0+j)*D_ + h*64 + d];
    et_t[d*PT + j] = bf16r(ev);
  }
  __syncthreads();
  int w = tid>>6, l = tid&63, lr = l&15, g4 = l>>4;
  f32x4 acc[4];
  #pragma unroll
  for (int ni=0;ni<4;ni++) acc[ni] = (f32x4){0.f,0.f,0.f,0.f};
  #pragma unroll
  for (int kk=0;kk<2;kk++){
    bf16x8 a = *(const bf16x8*)&et_t[(w*16+lr)*PT + kk*32 + g4*8];
    #pragma unroll
    for (int ni=0;ni<4;ni++){
      bf16x8 bb = *(const bf16x8*)&kt_t[(ni*16+lr)*PT + kk*32 + g4*8];
      acc[ni] = __builtin_amdgcn_mfma_f32_16x16x32_bf16(a, bb, acc[ni], 0,0,0);
    }
  }
  #pragma unroll
  for (int ni=0;ni<4;ni++)
    #pragma unroll
    for (int r=0;r<4;r++)
      uni[(w*16+g4*4+r)*PS + ni*16+lr] = acc[ni][r];
  __syncthreads();
  float* out = CS + ((size_t)bh*NCH + c)*4096;
  #pragma unroll
  for (int t=0;t<4;t++){
    int idx = tid + t*256;
    int r = idx>>4, s = idx&15;
    *(float4*)&out[r*64 + s*4] = *(float4*)&uni[r*PS + s*4];
  }
}

// ---------------- AR O1 per chunk (MFMA, inline carry over raw chunk sums) ----------------
__global__ __launch_bounds__(256) void ar_o1_mfma(
  const unsigned short* __restrict__ Qbf, const unsigned short* __restrict__ Kbf,
  const unsigned short* __restrict__ Xbf, const float* __restrict__ CF,
  const float* __restrict__ GC, const float* __restrict__ CS,
  float* __restrict__ O1)
{
  int bh = blockIdx.x, c = blockIdx.y;
  int b = bh >> 4, h = bh & 15;
  int row0 = b*L_ + c*CHUNK;
  __shared__ __align__(16) unsigned short q_t[64*PT];
  __shared__ __align__(16) unsigned short k_t[64*PT];
  __shared__ __align__(16) unsigned short vt_t[64*PT];   // V^T [e][j]
  __shared__ __align__(16) unsigned short st_t[64*PT];   // Sc^T [e][d] (carry)
  __shared__ __align__(16) float uni[64*PS];             // P stage / out stage
  unsigned short* p_t = (unsigned short*)uni;
  __shared__ float cf_s[64], gc_s[64];
  int tid = threadIdx.x;
  if (tid < 64) {
    cf_s[tid] = CF[(size_t)bh*L_ + c*CHUNK + tid];
    gc_s[tid] = GC[(size_t)bh*L_ + c*CHUNK + tid];
  }
  const unsigned short* qg = Qbf + (size_t)row0*D_ + h*64;
  const unsigned short* kg = Kbf + (size_t)row0*D_ + h*64;
  const unsigned short* vg = Xbf + (size_t)row0*D_ + h*64;
  const float* csb = CS + (size_t)bh*NCH*4096;
  // inline exclusive prefix: carry = sum of raw chunk sums CS[0..c-1]
  float carry[16];
  #pragma unroll
  for (int i=0;i<16;i++) carry[i] = 0.f;
  for (int c2=0;c2<c;c2++)
    #pragma unroll
    for (int i=0;i<16;i++)
      carry[i] += csb[(size_t)c2*4096 + tid + i*256];
  #pragma unroll
  for (int t=0;t<2;t++){
    int idx = tid + t*256;
    int j = idx>>3, s = idx&7;
    *(uint4*)&q_t[j*PT + s*8] = *(const uint4*)&qg[(size_t)j*D_ + s*8];
    *(uint4*)&k_t[j*PT + s*8] = *(const uint4*)&kg[(size_t)j*D_ + s*8];
  }
  #pragma unroll
  for (int t=0;t<16;t++){
    int idx = tid + t*256;
    int j = idx>>6, d = idx&63;
    vt_t[d*PT + j] = vg[(size_t)j*D_ + d];
  }
  #pragma unroll
  for (int i=0;i<16;i++){
    int idx = tid + i*256;
    st_t[(idx>>6)*PT + (idx&63)] = bf16r(carry[i]);
  }
  __syncthreads();
  int w = tid>>6, l = tid&63, lr = l&15, g4 = l>>4;
  // mfma1: P = causal(Q @ K^T) * cf
  f32x4 acc[4];
  #pragma unroll
  for (int ni=0;ni<4;ni++) acc[ni] = (f32x4){0.f,0.f,0.f,0.f};
  #pragma unroll
  for (int kk=0;kk<2;kk++){
    bf16x8 a = *(const bf16x8*)&q_t[(w*16+lr)*PT + kk*32 + g4*8];
    #pragma unroll
    for (int ni=0;ni<4;ni++){
      bf16x8 bb = *(const bf16x8*)&k_t[(ni*16+lr)*PT + kk*32 + g4*8];
      acc[ni] = __builtin_amdgcn_mfma_f32_16x16x32_bf16(a, bb, acc[ni], 0,0,0);
    }
  }
  #pragma unroll
  for (int ni=0;ni<4;ni++){
    int j = ni*16 + lr;
    float cf = cf_s[j];
    #pragma unroll
    for (int r=0;r<4;r++){
      int row = w*16 + g4*4 + r;
      float v = (j <= row) ? acc[ni][r]*cf : 0.f;
      p_t[row*PT + j] = bf16r(v);
    }
  }
  __syncthreads();
  // mfma2: O1 = Gc*(P@V + Q@Sc^T)
  #pragma unroll
  for (int ni=0;ni<4;ni++) acc[ni] = (f32x4){0.f,0.f,0.f,0.f};
  #pragma unroll
  for (int kk=0;kk<2;kk++){
    bf16x8 ap = *(const bf16x8*)&p_t[(w*16+lr)*PT + kk*32 + g4*8];
    bf16x8 aq = *(const bf16x8*)&q_t[(w*16+lr)*PT + kk*32 + g4*8];
    #pragma unroll
    for (int ni=0;ni<4;ni++){
      bf16x8 bv = *(const bf16x8*)&vt_t[(ni*16+lr)*PT + kk*32 + g4*8];
      bf16x8 bs = *(const bf16x8*)&st_t[(ni*16+lr)*PT + kk*32 + g4*8];
      acc[ni] = __builtin_amdgcn_mfma_f32_16x16x32_bf16(ap, bv, acc[ni], 0,0,0);
      acc[ni] = __builtin_amdgcn_mfma_f32_16x16x32_bf16(aq, bs, acc[ni], 0,0,0);
    }
  }
  __syncthreads();
  #pragma unroll
  for (int ni=0;ni<4;ni++)
    #pragma unroll
    for (int r=0;r<4;r++){
      int row = w*16 + g4*4 + r;
      uni[row*PS + ni*16 + lr] = gc_s[row]*acc[ni][r];
    }
  __syncthreads();
  #pragma unroll
  for (int t=0;t<4;t++){
    int idx = tid + t*256;
    int r = idx>>4, s = idx&15;
    *(float4*)&O1[(size_t)(row0+r)*D_ + h*64 + s*4] = *(float4*)&uni[r*PS + s*4];
  }
}

// ---------------- MA O2 per chunk (MFMA, inline carry); writes final bf16 O ----------------
__global__ __launch_bounds__(256) void ma_o2_mfma(
  const unsigned short* __restrict__ Qbf, const unsigned short* __restrict__ K2bf,
  const float* __restrict__ X, const float* __restrict__ CS,
  const float* __restrict__ O1, unsigned short* __restrict__ Obf)
{
  int bh = blockIdx.x, c = blockIdx.y;
  int b = bh >> 4, h = bh & 15;
  int row0 = b*L_ + c*CHUNK;
  __shared__ __align__(16) unsigned short q_t[64*PT];    // q2 [t][d]
  __shared__ __align__(16) unsigned short k_t[64*PT];    // k2 [j][d]
  __shared__ __align__(16) unsigned short et_t[64*PT];   // E^T [e][j]
  __shared__ __align__(16) unsigned short tt_t[64*PT];   // Tc^T [e][d] (carry)
  __shared__ __align__(16) float uni[64*PS];
  unsigned short* p_t = (unsigned short*)uni;
  int tid = threadIdx.x;
  const unsigned short* qg = Qbf  + (size_t)row0*D_ + h*64;
  const unsigned short* kg = K2bf + (size_t)row0*D_ + h*64;
  const float* csb = CS + (size_t)bh*NCH*4096;
  float carry[16];
  #pragma unroll
  for (int i=0;i<16;i++) carry[i] = 0.f;
  for (int c2=0;c2<c;c2++)
    #pragma unroll
    for (int i=0;i<16;i++)
      carry[i] += csb[(size_t)c2*4096 + tid + i*256];
  #pragma unroll
  for (int t=0;t<2;t++){
    int idx = tid + t*256;
    int j = idx>>3, s = idx&7;
    *(uint4*)&k_t[j*PT + s*8] = *(const uint4*)&kg[(size_t)j*D_ + s*8];
  }
  #pragma unroll
  for (int t=0;t<16;t++){
    int idx = tid + t*256;
    int j = idx>>6, d = idx&63;
    float qv = bf2f(qg[(size_t)j*D_ + d]);
    q_t[j*PT + d] = bf16r((qv > 0.f ? 0.02f*qv : qv) * 0.125f);
    float ev = 0.f;
    if (c*CHUNK + j < L_-1)
      ev = X[(size_t)(row0+j+1)*D_ + h*64 + d] - O1[(size_t)(row0+j)*D_ + h*64 + d];
    et_t[d*PT + j] = bf16r(ev);
  }
  #pragma unroll
  for (int i=0;i<16;i++){
    int idx = tid + i*256;
    tt_t[(idx>>6)*PT + (idx&63)] = bf16r(carry[i]);
  }
  __syncthreads();
  int w = tid>>6, l = tid&63, lr = l&15, g4 = l>>4;
  f32x4 acc[4];
  #pragma unroll
  for (int ni=0;ni<4;ni++) acc[ni] = (f32x4){0.f,0.f,0.f,0.f};
  #pragma unroll
  for (int kk=0;kk<2;kk++){
    bf16x8 a = *(const bf16x8*)&q_t[(w*16+lr)*PT + kk*32 + g4*8];
    #pragma unroll
    for (int ni=0;ni<4;ni++){
      bf16x8 bb = *(const bf16x8*)&k_t[(ni*16+lr)*PT + kk*32 + g4*8];
      acc[ni] = __builtin_amdgcn_mfma_f32_16x16x32_bf16(a, bb, acc[ni], 0,0,0);
    }
  }
  #pragma unroll
  for (int ni=0;ni<4;ni++){
    int j = ni*16 + lr;
    #pragma unroll
    for (int r=0;r<4;r++){
      int row = w*16 + g4*4 + r;
      float v = (j <= row) ? acc[ni][r] : 0.f;
      p_t[row*PT + j] = bf16r(v);
    }
  }
  __syncthreads();
  #pragma unroll
  for (int ni=0;ni<4;ni++) acc[ni] = (f32x4){0.f,0.f,0.f,0.f};
  #pragma unroll
  for (int kk=0;kk<2;kk++){
    bf16x8 ap = *(const bf16x8*)&p_t[(w*16+lr)*PT + kk*32 + g4*8];
    bf16x8 aq = *(const bf16x8*)&q_t[(w*16+lr)*PT + kk*32 + g4*8];
    #pragma unroll
    for (int ni=0;ni<4;ni++){
      bf16x8 be = *(const bf16x8*)&et_t[(ni*16+lr)*PT + kk*32 + g4*8];
      bf16x8 bt = *(const bf16x8*)&tt_t[(ni*16+lr)*PT + kk*32 + g4*8];
      acc[ni] = __builtin_amdgcn_mfma_f32_16x16x32_bf16(ap, be, acc[ni], 0,0,0);
      acc[ni] = __builtin_amdgcn_mfma_f32_16x16x32_bf16(aq, bt, acc[ni], 0,0,0);
    }
  }
  __syncthreads();
  #pragma unroll
  for (int ni=0;ni<4;ni++)
    #pragma unroll
    for (int r=0;r<4;r++){
      int row = w*16 + g4*4 + r;
      uni[row*PS + ni*16 + lr] = acc[ni][r];
    }
  __syncthreads();
  // final: Obf[t+1] = bf16(O1[t+1] + O2[t]); Obf[row0] handled by c==0 block
  #pragma unroll
  for (int t=0;t<4;t++){
    int idx = tid + t*256;
    int r = idx>>4, s = idx&15;
    if (c*CHUNK + r < L_-1) {
      const float4 gv = *(const float4*)&O1[(size_t)(row0+r+1)*D_ + h*64 + s*4];
      float4 uv = *(float4*)&uni[r*PS + s*4];
      ushort4 o;
      o.x = bf16r(gv.x+uv.x); o.y = bf16r(gv.y+uv.y);
      o.z = bf16r(gv.z+uv.z); o.w = bf16r(gv.w+uv.w);
      *(ushort4*)&Obf[(size_t)(row0+r+1)*D_ + h*64 + s*4] = o;
    }
  }
  if (c == 0 && tid < 16) {
    const float4 gv = *(const float4*)&O1[(size_t)row0*D_ + h*64 + tid*4];
    ushort4 o;
    o.x = bf16r(gv.x); o.y = bf16r(gv.y); o.z = bf16r(gv.z); o.w = bf16r(gv.w);
    *(ushort4*)&Obf[(size_t)row0*D_ + h*64 + tid*4] = o;
  }
}

extern "C" void kernel_launch(void* const* d_in, const int* in_sizes, int n_in,
                              void* d_out, int out_size, void* d_ws, size_t ws_size,
                              hipStream_t stream) {
  const float* x  = (const float*)d_in[0];
  const float* Wq = (const float*)d_in[1];
  const float* bq = (const float*)d_in[2];
  const float* Wk1= (const float*)d_in[3];
  const float* bk1= (const float*)d_in[4];
  const float* Wk2= (const float*)d_in[5];
  const float* bk2= (const float*)d_in[6];
  const float* Wg = (const float*)d_in[7];
  const float* bg = (const float*)d_in[8];
  const float* Ws = (const float*)d_in[9];
  const float* bs = (const float*)d_in[10];
  const float* Wp = (const float*)d_in[11];
  const float* bp = (const float*)d_in[12];
  float* out = (float*)d_out;

  float* ws = (float*)d_ws;
  size_t MD = (size_t)M_*D_;
  float* Qb  = ws;
  float* Kb  = Qb  + MD;
  float* K2b = Kb  + MD;
  float* O1b = K2b + MD;
  float* CSb = O1b + MD;                     // 32*16*4096 floats (raw chunk sums)
  float* GLb = CSb + (size_t)32*NCH*4096;
  float* RRb = GLb + (size_t)M_*H_;
  float* GCb = RRb + (size_t)M_*H_;
  float* CFb = GCb + (size_t)32*L_;
  unsigned short* Xbf   = (unsigned short*)(CFb + (size_t)32*L_);
  unsigned short* Qbfs  = Xbf  + MD;
  unsigned short* Kbfs  = Qbfs + MD;
  unsigned short* K2bfs = Kbfs + MD;
  unsigned short* Obf   = K2bfs+ MD;
  unsigned short* Wt0   = Obf + MD;
  unsigned short* Wt1   = Wt0 + (size_t)D_*D_;
  unsigned short* Wt2   = Wt1 + (size_t)D_*D_;
  unsigned short* Wt3   = Wt2 + (size_t)D_*D_;

  f32_to_bf16<<<2048, 256, 0, stream>>>(x, Xbf, (int)(MD/4));
  dim3 gt(16, 16, 4);
  convert_wt<<<gt, 256, 0, stream>>>(Wq, Wk1, Wk2, Wp, Wt0, Wt1, Wt2, Wt3);

  dim3 gg(M_/128, D_/64, 3);
  gemm3<<<gg, 256, 0, stream>>>(Xbf, Wt0, Wt1, Wt2, bq, bk1, bk2,
                                Qb, Kb, K2b, Qbfs, Kbfs, K2bfs);

  scalars_kernel<<<(M_*H_)/4, 256, 0, stream>>>(x, Kb, Wg, bg, Ws, bs, GLb, RRb);
  gl_scan<<<8, 256, 0, stream>>>(GLb, RRb, GCb, CFb);

  dim3 gc(32, NCH);
  ar_chunk_sum<<<gc, 256, 0, stream>>>(Kbfs, Xbf, CFb, CSb);
  ar_o1_mfma<<<gc, 256, 0, stream>>>(Qbfs, Kbfs, Xbf, CFb, GCb, CSb, O1b);

  ma_chunk_sum<<<gc, 256, 0, stream>>>(K2bfs, x, O1b, CSb);
  ma_o2_mfma<<<gc, 256, 0, stream>>>(Qbfs, K2bfs, x, CSb, O1b, Obf);

  dim3 go(M_/128, D_/64);
  gemm1<<<go, 256, 0, stream>>>(Obf, Wt3, bp, out);
}

// Round 8
// 184.731 us; speedup vs baseline: 6.7289x; 1.0807x over previous
//
#include <hip/hip_runtime.h>
#include <hip/hip_bf16.h>
#include <math.h>

#define B_  2
#define L_  1024
#define D_  1024
#define H_  16
#define DH_ 64
#define M_  (B_*L_)   // 2048
#define CHUNK 64
#define NCH (L_/CHUNK)   // 16
#define PT 72   // bf16 LDS tile pad (shorts): rows 144B, 16B-aligned
#define PS 76   // f32 LDS out-stage pad (floats): rows 304B, 16B-aligned

#define KSCALE (0.02f/32.0f)   // /sqrt(D) * 0.02

using bf16x8 = __attribute__((ext_vector_type(8))) short;
using f32x4  = __attribute__((ext_vector_type(4))) float;

__device__ __forceinline__ unsigned short bf16r(float f){
  union{float f; unsigned int u;} x; x.f = f;
  unsigned int r = x.u + 0x7FFF + ((x.u>>16)&1);
  return (unsigned short)(r>>16);
}
__device__ __forceinline__ float bf2f(unsigned short u){
  union{unsigned int u; float f;} x; x.u = ((unsigned int)u)<<16; return x.f;
}

// ---------------- all conversions in one launch ----------------
// z=0..3: W[K][N] fp32 -> T[N][K] bf16 (transpose).  z=4: x fp32 -> bf16 flat.
__global__ __launch_bounds__(256) void convert_all(
  const float* __restrict__ X,
  const float* __restrict__ W0, const float* __restrict__ W1,
  const float* __restrict__ W2, const float* __restrict__ W3,
  unsigned short* __restrict__ Xbf,
  unsigned short* __restrict__ T0, unsigned short* __restrict__ T1,
  unsigned short* __restrict__ T2, unsigned short* __restrict__ T3)
{
  int z = blockIdx.z;
  if (z == 4) {
    int row = blockIdx.x*64 + (threadIdx.x>>2);
    int col = blockIdx.y*64 + (threadIdx.x&3)*16;
    const float4* src = (const float4*)&X[(size_t)row*D_ + col];
    float4 a=src[0], b=src[1], c=src[2], d=src[3];
    unsigned short buf[16] = {
      bf16r(a.x),bf16r(a.y),bf16r(a.z),bf16r(a.w),
      bf16r(b.x),bf16r(b.y),bf16r(b.z),bf16r(b.w),
      bf16r(c.x),bf16r(c.y),bf16r(c.z),bf16r(c.w),
      bf16r(d.x),bf16r(d.y),bf16r(d.z),bf16r(d.w)};
    *(uint4*)&Xbf[(size_t)row*D_ + col]     = *(uint4*)&buf[0];
    *(uint4*)&Xbf[(size_t)row*D_ + col + 8] = *(uint4*)&buf[8];
    return;
  }
  if (blockIdx.x >= 16) return;
  const float* W = z==0?W0: z==1?W1: z==2?W2: W3;
  unsigned short* T = z==0?T0: z==1?T1: z==2?T2: T3;
  __shared__ float tile[64][65];
  int kBase = blockIdx.x*64, nBase = blockIdx.y*64;
  #pragma unroll
  for (int i=0;i<16;i++){
    int idx = threadIdx.x + i*256;
    int r = idx>>6, c = idx&63;
    tile[r][c] = W[(size_t)(kBase+r)*D_ + nBase+c];
  }
  __syncthreads();
  #pragma unroll
  for (int i=0;i<16;i++){
    int idx = threadIdx.x + i*256;
    int n = idx>>6, k = idx&63;
    T[(size_t)(nBase+n)*D_ + kBase+k] = bf16r(tile[k][n]);
  }
}

// ---------------- 128x128 MFMA GEMM (bf16 out only): 3 projections ----------------
__global__ __launch_bounds__(256) void gemm3(
  const unsigned short* __restrict__ A,
  const unsigned short* __restrict__ T0, const unsigned short* __restrict__ T1,
  const unsigned short* __restrict__ T2,
  const float* __restrict__ b0, const float* __restrict__ b1, const float* __restrict__ b2,
  unsigned short* __restrict__ F0, unsigned short* __restrict__ F1,
  unsigned short* __restrict__ F2)
{
  int z = blockIdx.z;
  const unsigned short* Bt = z==0?T0: z==1?T1: T2;
  const float* bias = z==0?b0: z==1?b1: b2;
  unsigned short* F = z==0?F0: z==1?F1: F2;
  int epi = (z==2) ? 1 : 0;
  int rowBase = blockIdx.x*128, colBase = blockIdx.y*128;

  __shared__ __align__(16) unsigned short As[128*32];
  __shared__ __align__(16) unsigned short Bs[128*32];
  int tid = threadIdx.x, w = tid>>6, l = tid&63;
  int lr = l&15, g4 = l>>4;
  int wr = w>>1, wc = w&1;
  f32x4 acc[4][4];
  #pragma unroll
  for (int mi=0;mi<4;mi++)
    #pragma unroll
    for (int ni=0;ni<4;ni++)
      acc[mi][ni] = (f32x4){0.f,0.f,0.f,0.f};

  for (int k0 = 0; k0 < D_; k0 += 32) {
    #pragma unroll
    for (int i=0;i<2;i++){
      int Fi = (w*2+i)*64 + l;
      int r = Fi>>2, c16 = Fi&3;
      int sc = c16 ^ ((r>>1)&3);
      const unsigned short* ga = A  + (size_t)(rowBase+r)*D_ + k0 + sc*8;
      const unsigned short* gb = Bt + (size_t)(colBase+r)*D_ + k0 + sc*8;
      __builtin_amdgcn_global_load_lds(
        (const __attribute__((address_space(1))) void*)ga,
        (__attribute__((address_space(3))) void*)(As + (size_t)(w*2+i)*512), 16, 0, 0);
      __builtin_amdgcn_global_load_lds(
        (const __attribute__((address_space(1))) void*)gb,
        (__attribute__((address_space(3))) void*)(Bs + (size_t)(w*2+i)*512), 16, 0, 0);
    }
    __syncthreads();
    bf16x8 af[4], bfr[4];
    #pragma unroll
    for (int mi=0;mi<4;mi++){
      int row = wr*64 + mi*16 + lr;
      af[mi] = *(const bf16x8*)(As + row*32 + ((g4 ^ ((row>>1)&3))*8));
    }
    #pragma unroll
    for (int ni=0;ni<4;ni++){
      int n = wc*64 + ni*16 + lr;
      bfr[ni] = *(const bf16x8*)(Bs + n*32 + ((g4 ^ ((n>>1)&3))*8));
    }
    #pragma unroll
    for (int mi=0;mi<4;mi++)
      #pragma unroll
      for (int ni=0;ni<4;ni++)
        acc[mi][ni] = __builtin_amdgcn_mfma_f32_16x16x32_bf16(af[mi], bfr[ni], acc[mi][ni], 0,0,0);
    __syncthreads();
  }

  #pragma unroll
  for (int mi=0;mi<4;mi++){
    #pragma unroll
    for (int ni=0;ni<4;ni++){
      int col = colBase + wc*64 + ni*16 + lr;
      float bv = bias[col];
      #pragma unroll
      for (int r=0;r<4;r++){
        int row = rowBase + wr*64 + mi*16 + g4*4 + r;
        float v = acc[mi][ni][r] + bv;
        if (epi) v = 1.f/(1.f + expf(-v*KSCALE));
        F[(size_t)row*D_ + col] = bf16r(v);
      }
    }
  }
}

// ---------------- 128x64 MFMA GEMM (fp32 out): output projection ----------------
__global__ __launch_bounds__(256) void gemm1(
  const unsigned short* __restrict__ A, const unsigned short* __restrict__ Bt,
  const float* __restrict__ bias, float* __restrict__ C)
{
  int rowBase = blockIdx.x*128, colBase = blockIdx.y*64;
  __shared__ __align__(16) unsigned short As[128*32];
  __shared__ __align__(16) unsigned short Bs[64*32];
  int tid = threadIdx.x, w = tid>>6, l = tid&63;
  int lr = l&15, g4 = l>>4;
  f32x4 acc[2][4];
  #pragma unroll
  for (int mi=0;mi<2;mi++)
    #pragma unroll
    for (int ni=0;ni<4;ni++)
      acc[mi][ni] = (f32x4){0.f,0.f,0.f,0.f};

  for (int k0 = 0; k0 < D_; k0 += 32) {
    #pragma unroll
    for (int i=0;i<2;i++){
      int F = (w*2+i)*64 + l;
      int r = F>>2, c16 = F&3;
      int sc = c16 ^ ((r>>1)&3);
      const unsigned short* g = A + (size_t)(rowBase+r)*D_ + k0 + sc*8;
      __builtin_amdgcn_global_load_lds(
        (const __attribute__((address_space(1))) void*)g,
        (__attribute__((address_space(3))) void*)(As + (size_t)(w*2+i)*512), 16, 0, 0);
    }
    {
      int F = w*64 + l;
      int r = F>>2, c16 = F&3;
      int sc = c16 ^ ((r>>1)&3);
      const unsigned short* g = Bt + (size_t)(colBase+r)*D_ + k0 + sc*8;
      __builtin_amdgcn_global_load_lds(
        (const __attribute__((address_space(1))) void*)g,
        (__attribute__((address_space(3))) void*)(Bs + (size_t)w*512), 16, 0, 0);
    }
    __syncthreads();
    bf16x8 af[2], bfr[4];
    #pragma unroll
    for (int mi=0;mi<2;mi++){
      int row = w*32 + mi*16 + lr;
      af[mi] = *(const bf16x8*)(As + row*32 + ((g4 ^ ((row>>1)&3))*8));
    }
    #pragma unroll
    for (int ni=0;ni<4;ni++){
      int n = ni*16 + lr;
      bfr[ni] = *(const bf16x8*)(Bs + n*32 + ((g4 ^ ((n>>1)&3))*8));
    }
    #pragma unroll
    for (int mi=0;mi<2;mi++)
      #pragma unroll
      for (int ni=0;ni<4;ni++)
        acc[mi][ni] = __builtin_amdgcn_mfma_f32_16x16x32_bf16(af[mi], bfr[ni], acc[mi][ni], 0,0,0);
    __syncthreads();
  }

  #pragma unroll
  for (int mi=0;mi<2;mi++){
    #pragma unroll
    for (int ni=0;ni<4;ni++){
      int col = colBase + ni*16 + lr;
      float bv = bias[col];
      #pragma unroll
      for (int r=0;r<4;r++){
        int row = rowBase + w*32 + mi*16 + g4*4 + r;
        C[(size_t)row*D_ + col] = acc[mi][ni][r] + bv;
      }
    }
  }
}

// ---------------- per-(b,l,h) scalar gates (K from bf16) ----------------
__global__ __launch_bounds__(256) void scalars_kernel(
  const float* __restrict__ X, const unsigned short* __restrict__ Kbf,
  const float* __restrict__ Wg, const float* __restrict__ bg,
  const float* __restrict__ Ws, const float* __restrict__ bs,
  float* __restrict__ GL, float* __restrict__ RR)
{
  int item = blockIdx.x * 4 + (threadIdx.x >> 6);
  int ln = threadIdx.x & 63;
  int row = item >> 4;
  int h = item & 15;
  float xv = X[(size_t)row*D_ + h*64 + ln];
  float kv = bf2f(Kbf[(size_t)row*D_ + h*64 + ln]);
  float gdot = xv * Wg[ln];
  float rdot = kv * Ws[ln];
  #pragma unroll
  for (int off = 32; off; off >>= 1) {
    gdot += __shfl_xor(gdot, off);
    rdot += __shfl_xor(rdot, off);
  }
  if (ln == 0) {
    float glogit = gdot + bg[0];
    float sg = 1.f/(1.f+expf(-glogit));
    sg = fmaxf(sg, 1e-6f);
    GL[item] = logf(sg);
    float rlogit = rdot + bs[0];
    RR[item] = rlogit / (1.f + expf(-rlogit));
  }
}

// ---------------- gate prefix scan ----------------
__global__ __launch_bounds__(256) void gl_scan(
  const float* __restrict__ GL, const float* __restrict__ RR,
  float* __restrict__ GC, float* __restrict__ CF)
{
  int bh = blockIdx.x * 4 + (threadIdx.x >> 6);
  int b = bh >> 4, h = bh & 15;
  int ln = threadIdx.x & 63;
  float carry = 0.f;
  for (int it = 0; it < 16; ++it) {
    int l = it*64 + ln;
    float x = GL[((size_t)(b*L_ + l))*H_ + h];
    #pragma unroll
    for (int off = 1; off < 64; off <<= 1) {
      float t = __shfl_up(x, off);
      if (ln >= off) x += t;
    }
    float tot = __shfl(x, 63);
    float cum = carry + x;
    carry += tot;
    float lc = fminf(fmaxf(cum, -30.f), 30.f);
    float gc = expf(lc) + 1e-6f;
    GC[(size_t)bh*L_ + l] = gc;
    CF[(size_t)bh*L_ + l] = RR[((size_t)(b*L_ + l))*H_ + h] / gc;
  }
}

// ---------------- AR chunk sum: CS[e][d] = sum_j cf_j*V[j][e]*K[j][d] ----------------
__global__ __launch_bounds__(256) void ar_chunk_sum(
  const unsigned short* __restrict__ Kbf, const unsigned short* __restrict__ Xbf,
  const float* __restrict__ CF, float* __restrict__ CS)
{
  int bh = blockIdx.x, c = blockIdx.y;
  int b = bh >> 4, h = bh & 15;
  int row0 = b*L_ + c*CHUNK;
  __shared__ __align__(16) unsigned short kt_t[64*PT];   // K^T [d][j]
  __shared__ __align__(16) unsigned short cv_t[64*PT];   // (cf*V)^T [e][j]
  __shared__ __align__(16) float uni[64*PS];
  __shared__ float cf_s[64];
  int tid = threadIdx.x;
  if (tid < 64) cf_s[tid] = CF[(size_t)bh*L_ + c*CHUNK + tid];
  __syncthreads();
  const unsigned short* kg = Kbf + (size_t)row0*D_ + h*64;
  const unsigned short* vg = Xbf + (size_t)row0*D_ + h*64;
  #pragma unroll
  for (int t=0;t<2;t++){
    int j = (tid>>3) + t*32;
    int d0 = (tid&7)*8;
    bf16x8 kv = *(const bf16x8*)&kg[(size_t)j*D_ + d0];
    bf16x8 vv = *(const bf16x8*)&vg[(size_t)j*D_ + d0];
    float cfj = cf_s[j];
    #pragma unroll
    for (int i=0;i<8;i++){
      kt_t[(d0+i)*PT + j] = (unsigned short)kv[i];
      cv_t[(d0+i)*PT + j] = bf16r(bf2f((unsigned short)vv[i]) * cfj);
    }
  }
  __syncthreads();
  int w = tid>>6, l = tid&63, lr = l&15, g4 = l>>4;
  f32x4 acc[4];
  #pragma unroll
  for (int ni=0;ni<4;ni++) acc[ni] = (f32x4){0.f,0.f,0.f,0.f};
  #pragma unroll
  for (int kk=0;kk<2;kk++){
    bf16x8 a = *(const bf16x8*)&cv_t[(w*16+lr)*PT + kk*32 + g4*8];
    #pragma unroll
    for (int ni=0;ni<4;ni++){
      bf16x8 bb = *(const bf16x8*)&kt_t[(ni*16+lr)*PT + kk*32 + g4*8];
      acc[ni] = __builtin_amdgcn_mfma_f32_16x16x32_bf16(a, bb, acc[ni], 0,0,0);
    }
  }
  #pragma unroll
  for (int ni=0;ni<4;ni++)
    #pragma unroll
    for (int r=0;r<4;r++)
      uni[(w*16+g4*4+r)*PS + ni*16+lr] = acc[ni][r];
  __syncthreads();
  float* out = CS + ((size_t)bh*NCH + c)*4096;
  #pragma unroll
  for (int t=0;t<4;t++){
    int idx = tid + t*256;
    int r = idx>>4, s = idx&15;
    *(float4*)&out[r*64 + s*4] = *(float4*)&uni[r*PS + s*4];
  }
}

// ---------------- MA chunk sum: CS[e][d] = sum_j E[j][e]*k2[j][d] ----------------
__global__ __launch_bounds__(256) void ma_chunk_sum(
  const unsigned short* __restrict__ K2bf, const unsigned short* __restrict__ Xbf,
  const float* __restrict__ O1, float* __restrict__ CS)
{
  int bh = blockIdx.x, c = blockIdx.y;
  int b = bh >> 4, h = bh & 15;
  int row0 = b*L_ + c*CHUNK;
  __shared__ __align__(16) unsigned short kt_t[64*PT];   // k2^T [d][j]
  __shared__ __align__(16) unsigned short et_t[64*PT];   // E^T [e][j]
  __shared__ __align__(16) float uni[64*PS];
  int tid = threadIdx.x;
  const unsigned short* kg = K2bf + (size_t)row0*D_ + h*64;
  #pragma unroll
  for (int t=0;t<2;t++){
    int j = (tid>>3) + t*32;
    int e0 = (tid&7)*8;
    bf16x8 kv = *(const bf16x8*)&kg[(size_t)j*D_ + e0];
    float ev[8] = {0.f,0.f,0.f,0.f,0.f,0.f,0.f,0.f};
    if (c*CHUNK + j < L_-1){
      bf16x8 xv = *(const bf16x8*)&Xbf[(size_t)(row0+j+1)*D_ + h*64 + e0];
      const float4* op = (const float4*)&O1[(size_t)(row0+j)*D_ + h*64 + e0];
      float4 o0 = op[0], o1v = op[1];
      ev[0]=bf2f((unsigned short)xv[0])-o0.x;  ev[1]=bf2f((unsigned short)xv[1])-o0.y;
      ev[2]=bf2f((unsigned short)xv[2])-o0.z;  ev[3]=bf2f((unsigned short)xv[3])-o0.w;
      ev[4]=bf2f((unsigned short)xv[4])-o1v.x; ev[5]=bf2f((unsigned short)xv[5])-o1v.y;
      ev[6]=bf2f((unsigned short)xv[6])-o1v.z; ev[7]=bf2f((unsigned short)xv[7])-o1v.w;
    }
    #pragma unroll
    for (int i=0;i<8;i++){
      kt_t[(e0+i)*PT + j] = (unsigned short)kv[i];
      et_t[(e0+i)*PT + j] = bf16r(ev[i]);
    }
  }
  __syncthreads();
  int w = tid>>6, l = tid&63, lr = l&15, g4 = l>>4;
  f32x4 acc[4];
  #pragma unroll
  for (int ni=0;ni<4;ni++) acc[ni] = (f32x4){0.f,0.f,0.f,0.f};
  #pragma unroll
  for (int kk=0;kk<2;kk++){
    bf16x8 a = *(const bf16x8*)&et_t[(w*16+lr)*PT + kk*32 + g4*8];
    #pragma unroll
    for (int ni=0;ni<4;ni++){
      bf16x8 bb = *(const bf16x8*)&kt_t[(ni*16+lr)*PT + kk*32 + g4*8];
      acc[ni] = __builtin_amdgcn_mfma_f32_16x16x32_bf16(a, bb, acc[ni], 0,0,0);
    }
  }
  #pragma unroll
  for (int ni=0;ni<4;ni++)
    #pragma unroll
    for (int r=0;r<4;r++)
      uni[(w*16+g4*4+r)*PS + ni*16+lr] = acc[ni][r];
  __syncthreads();
  float* out = CS + ((size_t)bh*NCH + c)*4096;
  #pragma unroll
  for (int t=0;t<4;t++){
    int idx = tid + t*256;
    int r = idx>>4, s = idx&15;
    *(float4*)&out[r*64 + s*4] = *(float4*)&uni[r*PS + s*4];
  }
}

// ---------------- AR O1 per chunk (inline carry, vectorized staging) ----------------
__global__ __launch_bounds__(256) void ar_o1_mfma(
  const unsigned short* __restrict__ Qbf, const unsigned short* __restrict__ Kbf,
  const unsigned short* __restrict__ Xbf, const float* __restrict__ CF,
  const float* __restrict__ GC, const float* __restrict__ CS,
  float* __restrict__ O1)
{
  int bh = blockIdx.x, c = blockIdx.y;
  int b = bh >> 4, h = bh & 15;
  int row0 = b*L_ + c*CHUNK;
  __shared__ __align__(16) unsigned short q_t[64*PT];
  __shared__ __align__(16) unsigned short k_t[64*PT];
  __shared__ __align__(16) unsigned short vt_t[64*PT];   // V^T [e][j]
  __shared__ __align__(16) unsigned short st_t[64*PT];   // Sc^T [e][d] (carry)
  __shared__ __align__(16) float uni[64*PS];
  unsigned short* p_t = (unsigned short*)uni;
  __shared__ float cf_s[64], gc_s[64];
  int tid = threadIdx.x;
  if (tid < 64) {
    cf_s[tid] = CF[(size_t)bh*L_ + c*CHUNK + tid];
    gc_s[tid] = GC[(size_t)bh*L_ + c*CHUNK + tid];
  }
  const unsigned short* qg = Qbf + (size_t)row0*D_ + h*64;
  const unsigned short* kg = Kbf + (size_t)row0*D_ + h*64;
  const unsigned short* vg = Xbf + (size_t)row0*D_ + h*64;
  const float* csb = CS + (size_t)bh*NCH*4096;
  // inline exclusive prefix over raw chunk sums: 16 consecutive elems/thread
  {
    float carry[16];
    #pragma unroll
    for (int i=0;i<16;i++) carry[i] = 0.f;
    const float* cb = csb + (size_t)tid*16;
    for (int c2=0;c2<c;c2++){
      const float4* p4 = (const float4*)(cb + (size_t)c2*4096);
      float4 a0=p4[0],a1=p4[1],a2=p4[2],a3=p4[3];
      carry[0]+=a0.x; carry[1]+=a0.y; carry[2]+=a0.z; carry[3]+=a0.w;
      carry[4]+=a1.x; carry[5]+=a1.y; carry[6]+=a1.z; carry[7]+=a1.w;
      carry[8]+=a2.x; carry[9]+=a2.y; carry[10]+=a2.z; carry[11]+=a2.w;
      carry[12]+=a3.x; carry[13]+=a3.y; carry[14]+=a3.z; carry[15]+=a3.w;
    }
    unsigned short buf[16];
    #pragma unroll
    for (int i=0;i<16;i++) buf[i] = bf16r(carry[i]);
    int row = tid>>2, col = (tid&3)*16;
    *(uint4*)&st_t[row*PT + col]     = *(uint4*)&buf[0];
    *(uint4*)&st_t[row*PT + col + 8] = *(uint4*)&buf[8];
  }
  #pragma unroll
  for (int t=0;t<2;t++){
    int idx = tid + t*256;
    int j = idx>>3, s = idx&7;
    *(uint4*)&q_t[j*PT + s*8] = *(const uint4*)&qg[(size_t)j*D_ + s*8];
    *(uint4*)&k_t[j*PT + s*8] = *(const uint4*)&kg[(size_t)j*D_ + s*8];
  }
  #pragma unroll
  for (int t=0;t<2;t++){
    int j = (tid>>3) + t*32;
    int e0 = (tid&7)*8;
    bf16x8 vv = *(const bf16x8*)&vg[(size_t)j*D_ + e0];
    #pragma unroll
    for (int i=0;i<8;i++) vt_t[(e0+i)*PT + j] = (unsigned short)vv[i];
  }
  __syncthreads();
  int w = tid>>6, l = tid&63, lr = l&15, g4 = l>>4;
  // mfma1: P = causal(Q @ K^T) * cf
  f32x4 acc[4];
  #pragma unroll
  for (int ni=0;ni<4;ni++) acc[ni] = (f32x4){0.f,0.f,0.f,0.f};
  #pragma unroll
  for (int kk=0;kk<2;kk++){
    bf16x8 a = *(const bf16x8*)&q_t[(w*16+lr)*PT + kk*32 + g4*8];
    #pragma unroll
    for (int ni=0;ni<4;ni++){
      bf16x8 bb = *(const bf16x8*)&k_t[(ni*16+lr)*PT + kk*32 + g4*8];
      acc[ni] = __builtin_amdgcn_mfma_f32_16x16x32_bf16(a, bb, acc[ni], 0,0,0);
    }
  }
  #pragma unroll
  for (int ni=0;ni<4;ni++){
    int j = ni*16 + lr;
    float cf = cf_s[j];
    #pragma unroll
    for (int r=0;r<4;r++){
      int row = w*16 + g4*4 + r;
      float v = (j <= row) ? acc[ni][r]*cf : 0.f;
      p_t[row*PT + j] = bf16r(v);
    }
  }
  __syncthreads();
  // mfma2: O1 = Gc*(P@V + Q@Sc^T)
  #pragma unroll
  for (int ni=0;ni<4;ni++) acc[ni] = (f32x4){0.f,0.f,0.f,0.f};
  #pragma unroll
  for (int kk=0;kk<2;kk++){
    bf16x8 ap = *(const bf16x8*)&p_t[(w*16+lr)*PT + kk*32 + g4*8];
    bf16x8 aq = *(const bf16x8*)&q_t[(w*16+lr)*PT + kk*32 + g4*8];
    #pragma unroll
    for (int ni=0;ni<4;ni++){
      bf16x8 bv = *(const bf16x8*)&vt_t[(ni*16+lr)*PT + kk*32 + g4*8];
      bf16x8 bs = *(const bf16x8*)&st_t[(ni*16+lr)*PT + kk*32 + g4*8];
      acc[ni] = __builtin_amdgcn_mfma_f32_16x16x32_bf16(ap, bv, acc[ni], 0,0,0);
      acc[ni] = __builtin_amdgcn_mfma_f32_16x16x32_bf16(aq, bs, acc[ni], 0,0,0);
    }
  }
  __syncthreads();
  #pragma unroll
  for (int ni=0;ni<4;ni++)
    #pragma unroll
    for (int r=0;r<4;r++){
      int row = w*16 + g4*4 + r;
      uni[row*PS + ni*16 + lr] = gc_s[row]*acc[ni][r];
    }
  __syncthreads();
  #pragma unroll
  for (int t=0;t<4;t++){
    int idx = tid + t*256;
    int r = idx>>4, s = idx&15;
    *(float4*)&O1[(size_t)(row0+r)*D_ + h*64 + s*4] = *(float4*)&uni[r*PS + s*4];
  }
}

// ---------------- MA O2 per chunk (inline carry); writes final bf16 O ----------------
__global__ __launch_bounds__(256) void ma_o2_mfma(
  const unsigned short* __restrict__ Qbf, const unsigned short* __restrict__ K2bf,
  const unsigned short* __restrict__ Xbf, const float* __restrict__ CS,
  const float* __restrict__ O1, unsigned short* __restrict__ Obf)
{
  int bh = blockIdx.x, c = blockIdx.y;
  int b = bh >> 4, h = bh & 15;
  int row0 = b*L_ + c*CHUNK;
  __shared__ __align__(16) unsigned short q_t[64*PT];    // q2 [t][d]
  __shared__ __align__(16) unsigned short k_t[64*PT];    // k2 [j][d]
  __shared__ __align__(16) unsigned short et_t[64*PT];   // E^T [e][j]
  __shared__ __align__(16) unsigned short tt_t[64*PT];   // Tc^T [e][d] (carry)
  __shared__ __align__(16) float uni[64*PS];
  unsigned short* p_t = (unsigned short*)uni;
  int tid = threadIdx.x;
  const unsigned short* qg = Qbf  + (size_t)row0*D_ + h*64;
  const unsigned short* kg = K2bf + (size_t)row0*D_ + h*64;
  const float* csb = CS + (size_t)bh*NCH*4096;
  {
    float carry[16];
    #pragma unroll
    for (int i=0;i<16;i++) carry[i] = 0.f;
    const float* cb = csb + (size_t)tid*16;
    for (int c2=0;c2<c;c2++){
      const float4* p4 = (const float4*)(cb + (size_t)c2*4096);
      float4 a0=p4[0],a1=p4[1],a2=p4[2],a3=p4[3];
      carry[0]+=a0.x; carry[1]+=a0.y; carry[2]+=a0.z; carry[3]+=a0.w;
      carry[4]+=a1.x; carry[5]+=a1.y; carry[6]+=a1.z; carry[7]+=a1.w;
      carry[8]+=a2.x; carry[9]+=a2.y; carry[10]+=a2.z; carry[11]+=a2.w;
      carry[12]+=a3.x; carry[13]+=a3.y; carry[14]+=a3.z; carry[15]+=a3.w;
    }
    unsigned short buf[16];
    #pragma unroll
    for (int i=0;i<16;i++) buf[i] = bf16r(carry[i]);
    int row = tid>>2, col = (tid&3)*16;
    *(uint4*)&tt_t[row*PT + col]     = *(uint4*)&buf[0];
    *(uint4*)&tt_t[row*PT + col + 8] = *(uint4*)&buf[8];
  }
  #pragma unroll
  for (int t=0;t<2;t++){
    int idx = tid + t*256;
    int j = idx>>3, s = idx&7;
    *(uint4*)&k_t[j*PT + s*8] = *(const uint4*)&kg[(size_t)j*D_ + s*8];
  }
  #pragma unroll
  for (int t=0;t<2;t++){
    int j = (tid>>3) + t*32;
    int d0 = (tid&7)*8;
    bf16x8 qv = *(const bf16x8*)&qg[(size_t)j*D_ + d0];
    unsigned short qb[8];
    #pragma unroll
    for (int i=0;i<8;i++){
      float q = bf2f((unsigned short)qv[i]);
      qb[i] = bf16r((q > 0.f ? 0.02f*q : q) * 0.125f);
    }
    *(uint4*)&q_t[j*PT + d0] = *(uint4*)&qb[0];
    float ev[8] = {0.f,0.f,0.f,0.f,0.f,0.f,0.f,0.f};
    if (c*CHUNK + j < L_-1){
      bf16x8 xv = *(const bf16x8*)&Xbf[(size_t)(row0+j+1)*D_ + h*64 + d0];
      const float4* op = (const float4*)&O1[(size_t)(row0+j)*D_ + h*64 + d0];
      float4 o0 = op[0], o1v = op[1];
      ev[0]=bf2f((unsigned short)xv[0])-o0.x;  ev[1]=bf2f((unsigned short)xv[1])-o0.y;
      ev[2]=bf2f((unsigned short)xv[2])-o0.z;  ev[3]=bf2f((unsigned short)xv[3])-o0.w;
      ev[4]=bf2f((unsigned short)xv[4])-o1v.x; ev[5]=bf2f((unsigned short)xv[5])-o1v.y;
      ev[6]=bf2f((unsigned short)xv[6])-o1v.z; ev[7]=bf2f((unsigned short)xv[7])-o1v.w;
    }
    #pragma unroll
    for (int i=0;i<8;i++) et_t[(d0+i)*PT + j] = bf16r(ev[i]);
  }
  __syncthreads();
  int w = tid>>6, l = tid&63, lr = l&15, g4 = l>>4;
  f32x4 acc[4];
  #pragma unroll
  for (int ni=0;ni<4;ni++) acc[ni] = (f32x4){0.f,0.f,0.f,0.f};
  #pragma unroll
  for (int kk=0;kk<2;kk++){
    bf16x8 a = *(const bf16x8*)&q_t[(w*16+lr)*PT + kk*32 + g4*8];
    #pragma unroll
    for (int ni=0;ni<4;ni++){
      bf16x8 bb = *(const bf16x8*)&k_t[(ni*16+lr)*PT + kk*32 + g4*8];
      acc[ni] = __builtin_amdgcn_mfma_f32_16x16x32_bf16(a, bb, acc[ni], 0,0,0);
    }
  }
  #pragma unroll
  for (int ni=0;ni<4;ni++){
    int j = ni*16 + lr;
    #pragma unroll
    for (int r=0;r<4;r++){
      int row = w*16 + g4*4 + r;
      float v = (j <= row) ? acc[ni][r] : 0.f;
      p_t[row*PT + j] = bf16r(v);
    }
  }
  __syncthreads();
  #pragma unroll
  for (int ni=0;ni<4;ni++) acc[ni] = (f32x4){0.f,0.f,0.f,0.f};
  #pragma unroll
  for (int kk=0;kk<2;kk++){
    bf16x8 ap = *(const bf16x8*)&p_t[(w*16+lr)*PT + kk*32 + g4*8];
    bf16x8 aq = *(const bf16x8*)&q_t[(w*16+lr)*PT + kk*32 + g4*8];
    #pragma unroll
    for (int ni=0;ni<4;ni++){
      bf16x8 be = *(const bf16x8*)&et_t[(ni*16+lr)*PT + kk*32 + g4*8];
      bf16x8 bt = *(const bf16x8*)&tt_t[(ni*16+lr)*PT + kk*32 + g4*8];
      acc[ni] = __builtin_amdgcn_mfma_f32_16x16x32_bf16(ap, be, acc[ni], 0,0,0);
      acc[ni] = __builtin_amdgcn_mfma_f32_16x16x32_bf16(aq, bt, acc[ni], 0,0,0);
    }
  }
  __syncthreads();
  #pragma unroll
  for (int ni=0;ni<4;ni++)
    #pragma unroll
    for (int r=0;r<4;r++){
      int row = w*16 + g4*4 + r;
      uni[row*PS + ni*16 + lr] = acc[ni][r];
    }
  __syncthreads();
  #pragma unroll
  for (int t=0;t<4;t++){
    int idx = tid + t*256;
    int r = idx>>4, s = idx&15;
    if (c*CHUNK + r < L_-1) {
      const float4 gv = *(const float4*)&O1[(size_t)(row0+r+1)*D_ + h*64 + s*4];
      float4 uv = *(float4*)&uni[r*PS + s*4];
      ushort4 o;
      o.x = bf16r(gv.x+uv.x); o.y = bf16r(gv.y+uv.y);
      o.z = bf16r(gv.z+uv.z); o.w = bf16r(gv.w+uv.w);
      *(ushort4*)&Obf[(size_t)(row0+r+1)*D_ + h*64 + s*4] = o;
    }
  }
  if (c == 0 && tid < 16) {
    const float4 gv = *(const float4*)&O1[(size_t)row0*D_ + h*64 + tid*4];
    ushort4 o;
    o.x = bf16r(gv.x); o.y = bf16r(gv.y); o.z = bf16r(gv.z); o.w = bf16r(gv.w);
    *(ushort4*)&Obf[(size_t)row0*D_ + h*64 + tid*4] = o;
  }
}

extern "C" void kernel_launch(void* const* d_in, const int* in_sizes, int n_in,
                              void* d_out, int out_size, void* d_ws, size_t ws_size,
                              hipStream_t stream) {
  const float* x  = (const float*)d_in[0];
  const float* Wq = (const float*)d_in[1];
  const float* bq = (const float*)d_in[2];
  const float* Wk1= (const float*)d_in[3];
  const float* bk1= (const float*)d_in[4];
  const float* Wk2= (const float*)d_in[5];
  const float* bk2= (const float*)d_in[6];
  const float* Wg = (const float*)d_in[7];
  const float* bg = (const float*)d_in[8];
  const float* Ws = (const float*)d_in[9];
  const float* bs = (const float*)d_in[10];
  const float* Wp = (const float*)d_in[11];
  const float* bp = (const float*)d_in[12];
  float* out = (float*)d_out;

  float* ws = (float*)d_ws;
  size_t MD = (size_t)M_*D_;
  float* O1b = ws;
  float* CSb = O1b + MD;                     // 32*16*4096 floats (raw chunk sums)
  float* GLb = CSb + (size_t)32*NCH*4096;
  float* RRb = GLb + (size_t)M_*H_;
  float* GCb = RRb + (size_t)M_*H_;
  float* CFb = GCb + (size_t)32*L_;
  unsigned short* Xbf   = (unsigned short*)(CFb + (size_t)32*L_);
  unsigned short* Qbfs  = Xbf  + MD;
  unsigned short* Kbfs  = Qbfs + MD;
  unsigned short* K2bfs = Kbfs + MD;
  unsigned short* Obf   = K2bfs+ MD;
  unsigned short* Wt0   = Obf + MD;
  unsigned short* Wt1   = Wt0 + (size_t)D_*D_;
  unsigned short* Wt2   = Wt1 + (size_t)D_*D_;
  unsigned short* Wt3   = Wt2 + (size_t)D_*D_;

  dim3 gcv(32, 16, 5);
  convert_all<<<gcv, 256, 0, stream>>>(x, Wq, Wk1, Wk2, Wp, Xbf, Wt0, Wt1, Wt2, Wt3);

  dim3 gg(M_/128, D_/128, 3);
  gemm3<<<gg, 256, 0, stream>>>(Xbf, Wt0, Wt1, Wt2, bq, bk1, bk2, Qbfs, Kbfs, K2bfs);

  scalars_kernel<<<(M_*H_)/4, 256, 0, stream>>>(x, Kbfs, Wg, bg, Ws, bs, GLb, RRb);
  gl_scan<<<8, 256, 0, stream>>>(GLb, RRb, GCb, CFb);

  dim3 gc(32, NCH);
  ar_chunk_sum<<<gc, 256, 0, stream>>>(Kbfs, Xbf, CFb, CSb);
  ar_o1_mfma<<<gc, 256, 0, stream>>>(Qbfs, Kbfs, Xbf, CFb, GCb, CSb, O1b);

  ma_chunk_sum<<<gc, 256, 0, stream>>>(K2bfs, Xbf, O1b, CSb);
  ma_o2_mfma<<<gc, 256, 0, stream>>>(Qbfs, K2bfs, Xbf, CSb, O1b, Obf);

  dim3 go(M_/128, D_/64);
  gemm1<<<go, 256, 0, stream>>>(Obf, Wt3, bp, out);
}